// Round 8
// baseline (694.985 us; speedup 1.0000x reference)
//
#include <hip/hip_runtime.h>
#include <cstdio>
#include <cstdint>

using u16 = unsigned short;
typedef __bf16 bf16x8 __attribute__((ext_vector_type(8)));
typedef unsigned short ushort8 __attribute__((ext_vector_type(8)));
typedef float f32x4 __attribute__((ext_vector_type(4)));

#define GLOBAL_AS __attribute__((address_space(1)))
#define LDS_AS __attribute__((address_space(3)))

__device__ __forceinline__ float bf2f(u16 h) {
  return __uint_as_float(((unsigned)h) << 16);
}
__device__ __forceinline__ u16 f2bf(float f) {
  unsigned u = __float_as_uint(f);
  u += 0x7FFFu + ((u >> 16) & 1u);
  return (u16)(u >> 16);
}

__device__ __forceinline__ void async_copy16(void* lds, const void* g) {
  __builtin_amdgcn_global_load_lds((const GLOBAL_AS unsigned int*)g,
                                   (LDS_AS unsigned int*)lds, 16, 0, 0);
}

// ---------------- block reduction helpers (blockDim = 256) ----------------
__device__ __forceinline__ float block_sum(float v, float* red) {
#pragma unroll
  for (int o = 32; o >= 1; o >>= 1) v += __shfl_xor(v, o);
  __syncthreads();
  if ((threadIdx.x & 63) == 0) red[threadIdx.x >> 6] = v;
  __syncthreads();
  return red[0] + red[1] + red[2] + red[3];
}

// ---------------- merged f32 -> bf16 converts (4 ranges, 1 launch) ----------------
__global__ __launch_bounds__(256) void cvt4_kernel(
    const float* __restrict__ s0, u16* __restrict__ d0,
    const float* __restrict__ s1, u16* __restrict__ d1,
    const float* __restrict__ s2, u16* __restrict__ d2,
    const float* __restrict__ s3, u16* __restrict__ d3) {
  const float* s; u16* d; long n; long b0; long nb;
  const int b = blockIdx.x;
  if (b < 2048)      { s = s0; d = d0; n = 37748736L; b0 = b;        nb = 2048; }
  else if (b < 2816) { s = s1; d = d1; n = 3145728L;  b0 = b - 2048; nb = 768; }
  else if (b < 3072) { s = s2; d = d2; n = 1048576L;  b0 = b - 2816; nb = 256; }
  else               { s = s3; d = d3; n = 143360L;   b0 = b - 3072; nb = 35; }
  long i = (b0 * 256 + threadIdx.x) * 4;
  const long stride = nb * 1024;
  for (; i < n; i += stride) {
    float4 v = *(const float4*)(s + i);
    ushort4 o;
    o.x = f2bf(v.x); o.y = f2bf(v.y); o.z = f2bf(v.z); o.w = f2bf(v.w);
    *(ushort4*)(d + i) = o;
  }
}

// =================================================================================
// Fused K+V+Q projection GEMM — 256x256 8-wave 4-phase schedule (round-6 proven).
// =================================================================================
template <int VTD>
__global__ __launch_bounds__(512, 2) void gemm_kvq_kernel(
    const u16* __restrict__ A, const u16* __restrict__ Bkv,
    const u16* __restrict__ Aq, const u16* __restrict__ Bq,
    u16* __restrict__ Ck, u16* __restrict__ Cvp, u16* __restrict__ Vt,
    u16* __restrict__ Cq,
    const float* __restrict__ bias, const float* __restrict__ biasq) {
  __shared__ char smem[131072];  // dbuf d: A at d*65536, B at d*65536+32768
  const int bid = blockIdx.x;
  const int t = threadIdx.x;
  const int wid = t >> 6, l = t & 63;
  const int wm = wid >> 2, wn = wid & 3;
  const int lr = l & 15, lg = l >> 4, lr7 = lr & 7;

  int mt = 0, nt = 0, qb = -1;
  const u16* Abase; const u16* Bbase; const float* bias_b;
  if (bid < 1152) {
    const int wgid = (bid & 7) * 144 + (bid >> 3);  // XCD swizzle (1152 = 8*144)
    mt = wgid >> 3; nt = wgid & 7;                  // nt fastest: A-panel L2 reuse
    Abase = A + (size_t)mt * 256 * 1024;
    Bbase = Bkv + (size_t)nt * 256 * 1024;
    bias_b = bias + nt * 256;
  } else {
    qb = bid - 1152;  // 0..3
    Abase = Aq;
    Bbase = Bq + (size_t)qb * 256 * 1024;
    bias_b = biasq + qb * 256;
  }

  const int srow = t >> 3;
  const int scx = (t & 7) ^ (srow & 7);
  const char* Asrc = (const char*)Abase + (size_t)srow * 2048 + (scx << 4);
  const char* Bsrc = (const char*)Bbase + (size_t)srow * 2048 + (scx << 4);
  const int wb = wid << 10;

  f32x4 acc[8][4] = {};

#define SA(d, r, kt) async_copy16(smem + (d)*65536 + (r)*8192 + wb, \
                                  Asrc + (size_t)(r)*131072 + (size_t)(kt)*128)
#define SB(d, r, kt) async_copy16(smem + (d)*65536 + 32768 + (r)*8192 + wb, \
                                  Bsrc + (size_t)(r)*131072 + (size_t)(kt)*128)

#define RA(d, half)                                                          \
  _Pragma("unroll")                                                          \
  for (int i = 0; i < 4; ++i) {                                              \
    const int row = wm * 128 + ((half)*4 + i) * 16 + lr;                     \
    af[i][0] = *(const bf16x8*)(smem + (d)*65536 + (row << 7) + ((lg ^ lr7) << 4));       \
    af[i][1] = *(const bf16x8*)(smem + (d)*65536 + (row << 7) + (((4 | lg) ^ lr7) << 4)); \
  }

#define RB(d, half)                                                          \
  _Pragma("unroll")                                                          \
  for (int j = 0; j < 2; ++j) {                                              \
    const int row = wn * 64 + ((half)*2 + j) * 16 + lr;                      \
    bfr[j][0] = *(const bf16x8*)(smem + (d)*65536 + 32768 + (row << 7) + ((lg ^ lr7) << 4));       \
    bfr[j][1] = *(const bf16x8*)(smem + (d)*65536 + 32768 + (row << 7) + (((4 | lg) ^ lr7) << 4)); \
  }

#define MM(mh, nh)                                                           \
  __builtin_amdgcn_s_setprio(1);                                             \
  _Pragma("unroll")                                                          \
  for (int ks = 0; ks < 2; ++ks)                                             \
    _Pragma("unroll")                                                        \
    for (int i = 0; i < 4; ++i)                                              \
      _Pragma("unroll")                                                      \
      for (int j = 0; j < 2; ++j)                                            \
        acc[(mh)*4 + i][(nh)*2 + j] = __builtin_amdgcn_mfma_f32_16x16x32_bf16( \
            af[i][ks], bfr[j][ks], acc[(mh)*4 + i][(nh)*2 + j], 0, 0, 0);    \
  __builtin_amdgcn_s_setprio(0);

  SA(0, 0, 0); SA(0, 1, 0); SA(0, 2, 0); SA(0, 3, 0);
  SB(0, 0, 0); SB(0, 1, 0); SB(0, 2, 0); SB(0, 3, 0);
  SA(1, 0, 1); SA(1, 2, 1);
  asm volatile("s_waitcnt vmcnt(2)" ::: "memory");
  __builtin_amdgcn_s_barrier();
  asm volatile("" ::: "memory");

#pragma unroll 1
  for (int kt = 0; kt < 16; ++kt) {
    const int cur = kt & 1, nxt = cur ^ 1;
    const bool pf1 = (kt < 15), pf2 = (kt < 14);
    bf16x8 af[4][2], bfr[2][2];
    RA(cur, 0);
    RB(cur, 0);
    if (pf1) { SB(nxt, 0, kt + 1); SB(nxt, 1, kt + 1); }
    __builtin_amdgcn_s_barrier();
    asm volatile("s_waitcnt lgkmcnt(0)" ::: "memory");
    MM(0, 0);
    __builtin_amdgcn_s_barrier();
    RB(cur, 1);
    if (pf1) { SB(nxt, 2, kt + 1); SB(nxt, 3, kt + 1); }
    __builtin_amdgcn_s_barrier();
    asm volatile("s_waitcnt lgkmcnt(0)" ::: "memory");
    MM(0, 1);
    if (pf1) asm volatile("s_waitcnt vmcnt(6)" ::: "memory");
    __builtin_amdgcn_s_barrier();
    RA(cur, 1);
    if (pf1) { SA(nxt, 1, kt + 1); SA(nxt, 3, kt + 1); }
    __builtin_amdgcn_s_barrier();
    asm volatile("s_waitcnt lgkmcnt(0)" ::: "memory");
    MM(1, 1);
    __builtin_amdgcn_s_barrier();
    RB(cur, 0);
    if (pf2) { SA(cur, 0, kt + 2); SA(cur, 2, kt + 2); }
    __builtin_amdgcn_s_barrier();
    asm volatile("s_waitcnt lgkmcnt(0)" ::: "memory");
    MM(1, 0);
    if (pf2)      asm volatile("s_waitcnt vmcnt(4)" ::: "memory");
    else if (pf1) asm volatile("s_waitcnt vmcnt(0)" ::: "memory");
    __builtin_amdgcn_s_barrier();
  }
#undef SA
#undef SB
#undef RA
#undef RB
#undef MM

  // ---------------- epilogue ----------------
  if (VTD && qb < 0 && nt >= 4) {
    u16* T = (u16*)smem;
    const int vc2 = t >> 1, seg = t & 1;
    const int vglob = (nt - 4) * 256 + vc2;
    const int h2 = vglob >> 7, d2 = vglob & 127;
#pragma unroll 1
    for (int mh = 0; mh < 2; ++mh) {
      __syncthreads();
      if (wm == mh) {
#pragma unroll
        for (int ni = 0; ni < 4; ++ni) {
          const int vc = wn * 64 + ni * 16 + lr;
          const float bv = bias_b[vc];
#pragma unroll
          for (int mi = 0; mi < 8; ++mi) {
            const int ml = mi * 16 + lg * 4;
            ushort4 pk;
            pk.x = f2bf(acc[mi][ni][0] + bv);
            pk.y = f2bf(acc[mi][ni][1] + bv);
            pk.z = f2bf(acc[mi][ni][2] + bv);
            pk.w = f2bf(acc[mi][ni][3] + bv);
            *(ushort4*)(T + (size_t)vc * 136 + ml) = pk;
          }
        }
      }
      __syncthreads();
      const int mg0 = mt * 256 + mh * 128 + seg * 64;
      const int bb = (unsigned)mg0 / 576u;
      const int k0 = mg0 - bb * 576;
      u16* dst = Vt + ((size_t)(bb * 8 + h2) * 128 + d2) * 576 + k0;
      const u16* src = T + (size_t)vc2 * 136 + seg * 64;
#pragma unroll
      for (int i2 = 0; i2 < 8; ++i2)
        *(uint4*)(dst + i2 * 8) = *(const uint4*)(src + i2 * 8);
    }
  } else {
    u16* D; int cb0;
    if (qb >= 0)      { D = Cq;  cb0 = qb * 256; }
    else if (nt < 4)  { D = Ck;  cb0 = nt * 256; }
    else              { D = Cvp; cb0 = (nt - 4) * 256; }
#pragma unroll
    for (int ni = 0; ni < 4; ++ni) {
      const int nc = wn * 64 + ni * 16 + lr;
      const float bv = bias_b[nc];
      const int col = cb0 + nc;
#pragma unroll
      for (int mi = 0; mi < 8; ++mi) {
#pragma unroll
        for (int rg = 0; rg < 4; ++rg) {
          const size_t m = (size_t)mt * 256 + wm * 128 + mi * 16 + lg * 4 + rg;
          D[m * 1024 + col] = f2bf(acc[mi][ni][rg] + bv);
        }
      }
    }
  }
}

// =================================================================================
// Generic deep-pipelined batched GEMM (round-2 proven loop; used for S, out-proj)
// =================================================================================
template <int OUTF32>
__global__ __launch_bounds__(512, 2) void gemm_big_kernel(
    const u16* __restrict__ A, const u16* __restrict__ B, void* __restrict__ Cv,
    const float* __restrict__ bias, float scale,
    int KT, int ntx, int Mlim, int Nlim,
    long lda, long ldb, long ldc, int bdiv,
    long sA0, long sA1, long sB0, long sB1, long sC0, long sC1) {
  __shared__ u16 lds[3][24576];
  const int bid = blockIdx.x;
  const int bh = blockIdx.y;
  const int bb0 = bh / bdiv, bb1 = bh % bdiv;
  const int mt = bid / ntx, nt = bid % ntx;
  const int t = threadIdx.x;
  const int wid = t >> 6, l = t & 63;
  const int wr = wid >> 1, wc = wid & 1;
  const int lr = l & 15, lg = l >> 4, lr7 = lr & 7;

  const long ldab = lda * 2, ldbb = ldb * 2;
  const u16* Abase = A + (long)bb0 * sA0 + (long)bb1 * sA1 + (long)mt * 256 * lda;
  const u16* Bbase = B + (long)bb0 * sB0 + (long)bb1 * sB1 + (long)nt * 128 * ldb;

  const int srow = t >> 3;
  const int scx = (t & 7) ^ (srow & 7);
  const char* Asrc = (const char*)Abase + (long)srow * ldab + (scx << 4);
  const char* Bsrc = (const char*)Bbase + (long)srow * ldbb + (scx << 4);
  const int wbA = wid << 10;

  char* b0 = (char*)lds[0];
  char* b1 = (char*)lds[1];
  char* b2 = (char*)lds[2];

  f32x4 acc[4][4] = {};

#define STAGE3G(dst, kt, part)                                              \
  {                                                                         \
    const long ko = (long)(kt) * 128;                                       \
    if ((part) == 0) {                                                      \
      async_copy16((dst) + wbA,          Asrc + ko);                        \
      async_copy16((dst) + 8192 + wbA,   Asrc + 64 * ldab + ko);            \
      async_copy16((dst) + 16384 + wbA,  Asrc + 128 * ldab + ko);           \
    } else {                                                                \
      async_copy16((dst) + 24576 + wbA,  Asrc + 192 * ldab + ko);           \
      async_copy16((dst) + 32768 + wbA,  Bsrc + ko);                        \
      async_copy16((dst) + 40960 + wbA,  Bsrc + 64 * ldbb + ko);            \
    }                                                                       \
  }

#define COMPUTE_KS(p, KS)                                                   \
  {                                                                         \
    const int ccol = (((KS) << 2) | lg) ^ lr7;                              \
    const char* pA = (p) + (((wr << 6) + lr) << 7) + (ccol << 4);           \
    const char* pB = (p) + 32768 + (((wc << 6) + lr) << 7) + (ccol << 4);   \
    bf16x8 af[4], bfr[4];                                                   \
    _Pragma("unroll")                                                       \
    for (int i = 0; i < 4; ++i) {                                           \
      af[i]  = *(const bf16x8*)(pA + i * 2048);                             \
      bfr[i] = *(const bf16x8*)(pB + i * 2048);                             \
    }                                                                       \
    __builtin_amdgcn_s_setprio(1);                                          \
    _Pragma("unroll")                                                       \
    for (int mi = 0; mi < 4; ++mi)                                          \
      _Pragma("unroll")                                                     \
      for (int ni = 0; ni < 4; ++ni)                                        \
        acc[mi][ni] = __builtin_amdgcn_mfma_f32_16x16x32_bf16(              \
            af[mi], bfr[ni], acc[mi][ni], 0, 0, 0);                         \
    __builtin_amdgcn_s_setprio(0);                                          \
  }

  STAGE3G(b0, 0, 0); STAGE3G(b0, 0, 1);
  STAGE3G(b1, 1, 0); STAGE3G(b1, 1, 1);
  asm volatile("s_waitcnt vmcnt(6)" ::: "memory");
  __builtin_amdgcn_s_barrier();
  asm volatile("" ::: "memory");

  char* p0 = b0; char* p1 = b1; char* p2 = b2;
#pragma unroll 1
  for (int kt = 0; kt < KT; ++kt) {
    const bool pf = (kt < KT - 2);
    if (pf) STAGE3G(p2, kt + 2, 0);
    COMPUTE_KS(p0, 0);
    if (pf) STAGE3G(p2, kt + 2, 1);
    COMPUTE_KS(p0, 1);
    if (kt < KT - 1) {
      if (pf) asm volatile("s_waitcnt vmcnt(6)" ::: "memory");
      else    asm volatile("s_waitcnt vmcnt(0)" ::: "memory");
      __builtin_amdgcn_s_barrier();
      asm volatile("" ::: "memory");
    }
    char* tmp = p0; p0 = p1; p1 = p2; p2 = tmp;
  }
#undef STAGE3G
#undef COMPUTE_KS

  const long cBase = (long)bb0 * sC0 + (long)bb1 * sC1;
  const int mr0 = mt * 256 + wr * 64 + lg * 4;
  const int nc0 = nt * 128 + wc * 64 + lr;
#pragma unroll
  for (int ni = 0; ni < 4; ++ni) {
    const int n = nc0 + ni * 16;
    if (n >= Nlim) continue;
    const float bv = bias ? bias[n] : 0.0f;
#pragma unroll
    for (int mi = 0; mi < 4; ++mi) {
#pragma unroll
      for (int rg = 0; rg < 4; ++rg) {
        const int m = mr0 + mi * 16 + rg;
        if (m >= Mlim) continue;
        const float v = acc[mi][ni][rg] * scale + bv;
        if (OUTF32) ((float*)Cv)[cBase + (long)m * ldc + n] = v;
        else        ((u16*)Cv)[cBase + (long)m * ldc + n] = f2bf(v);
      }
    }
  }
}

// ---------------- V transpose (fallback path only) ----------------
__global__ __launch_bounds__(256) void transpose_v_kernel(const u16* __restrict__ V,
                                                          u16* __restrict__ Vt) {
  __shared__ u16 tile[64][65];
  const int k0 = blockIdx.x * 64;
  const int c0 = blockIdx.y * 64;
  const int b = blockIdx.z;
  const int t = threadIdx.x;
  const int tx = t & 15, ty = t >> 4;
  const u16* Vb = V + (size_t)(b * 576) * 1024;
#pragma unroll
  for (int i = 0; i < 4; ++i) {
    const int k = ty + i * 16;
    const u16* src = Vb + (size_t)(k0 + k) * 1024 + c0 + tx * 4;
    ushort2 v01 = *(const ushort2*)src;
    ushort2 v23 = *(const ushort2*)(src + 2);
    tile[k][tx * 4 + 0] = v01.x; tile[k][tx * 4 + 1] = v01.y;
    tile[k][tx * 4 + 2] = v23.x; tile[k][tx * 4 + 3] = v23.y;
  }
  __syncthreads();
  const int h = c0 >> 7, d0 = c0 & 127;
  u16* VtB = Vt + ((size_t)(b * 8 + h) * 128 + d0) * 576 + k0;
#pragma unroll
  for (int i = 0; i < 4; ++i) {
    const int d = ty + i * 16;
    u16* dst = VtB + (size_t)d * 576 + tx * 4;
    ushort2 a, bb2;
    a.x = tile[tx * 4 + 0][d]; a.y = tile[tx * 4 + 1][d];
    bb2.x = tile[tx * 4 + 2][d]; bb2.y = tile[tx * 4 + 3][d];
    *(ushort2*)dst = a; *(ushort2*)(dst + 2) = bb2;
  }
}

// =================================================================================
// softmax_pm: vectorized (G13). Block (b,c)=64x14, 512 thr = 8 waves = 8 heads.
// Row of 576 bf16 = 72 chunks of 8; lane l owns chunks {l} and {64+l | l<8}.
// pl layout [h][72 chunks][9 f32] (pad 1) -> write banks 9l%32, 9 coprime 32 ->
// <=2-way (free). Emits head-mean attnOut + query-mean Pm (no P write-back).
// =================================================================================
__global__ __launch_bounds__(512) void softmax_pm_kernel(const u16* __restrict__ SP,
                                                         float* __restrict__ attnOut,
                                                         u16* __restrict__ Pm) {
  const int b = blockIdx.x, c = blockIdx.y;
  const int h = threadIdx.x >> 6, l = threadIdx.x & 63;
  const bool ex = (l < 8);
  __shared__ float pl[8][72][9];  // 20736 B
  float pacc[16] = {};
#pragma unroll 1
  for (int qq = 0; qq < 10; ++qq) {
    const u16* row = SP + ((size_t)((b * 8 + h) * 144 + c * 10 + qq)) * 576;
    ushort8 v0 = *(const ushort8*)(row + l * 8);
    ushort8 v1 = {0, 0, 0, 0, 0, 0, 0, 0};
    if (ex) v1 = *(const ushort8*)(row + 512 + l * 8);
    float x[16];
#pragma unroll
    for (int i = 0; i < 8; ++i) { x[i] = bf2f(v0[i]); x[8 + i] = bf2f(v1[i]); }
    float m = x[0];
#pragma unroll
    for (int i = 1; i < 8; ++i) m = fmaxf(m, x[i]);
    if (ex)
#pragma unroll
      for (int i = 8; i < 16; ++i) m = fmaxf(m, x[i]);
#pragma unroll
    for (int o = 32; o >= 1; o >>= 1) m = fmaxf(m, __shfl_xor(m, o));
    float e[16], s = 0.f;
#pragma unroll
    for (int i = 0; i < 8; ++i) { e[i] = expf(x[i] - m); s += e[i]; }
    if (ex) {
#pragma unroll
      for (int i = 8; i < 16; ++i) { e[i] = expf(x[i] - m); s += e[i]; }
    }
#pragma unroll
    for (int o = 32; o >= 1; o >>= 1) s += __shfl_xor(s, o);
    const float inv = 1.f / s;
#pragma unroll
    for (int i = 0; i < 8; ++i) {
      const float p = e[i] * inv;
      pacc[i] += p;
      pl[h][l][i] = p;
    }
    if (ex) {
#pragma unroll
      for (int i = 0; i < 8; ++i) {
        const float p = e[8 + i] * inv;
        pacc[8 + i] += p;
        pl[h][64 + l][i] = p;
      }
    }
    __syncthreads();
    float* out = attnOut + ((size_t)(b * 140 + c * 10 + qq)) * 576;
    {
      const int j = threadIdx.x;
      float a = 0.f;
#pragma unroll
      for (int hh = 0; hh < 8; ++hh) a += pl[hh][j >> 3][j & 7];
      out[j] = a * 0.125f;
      if (j < 64) {
        const int j2 = j + 512;
        float a2 = 0.f;
#pragma unroll
        for (int hh = 0; hh < 8; ++hh) a2 += pl[hh][j2 >> 3][j2 & 7];
        out[j2] = a2 * 0.125f;
      }
    }
    __syncthreads();  // pl reused next qq
  }
  // query-mean -> Pm (bf16), vectorized 16B stores
  u16* pm = Pm + ((size_t)((b * 8 + h) * 14 + c)) * 576;
  ushort4 pk0, pk1;
  pk0.x = f2bf(pacc[0] * 0.1f); pk0.y = f2bf(pacc[1] * 0.1f);
  pk0.z = f2bf(pacc[2] * 0.1f); pk0.w = f2bf(pacc[3] * 0.1f);
  pk1.x = f2bf(pacc[4] * 0.1f); pk1.y = f2bf(pacc[5] * 0.1f);
  pk1.z = f2bf(pacc[6] * 0.1f); pk1.w = f2bf(pacc[7] * 0.1f);
  *(ushort4*)(pm + l * 8) = pk0;
  *(ushort4*)(pm + l * 8 + 4) = pk1;
  if (ex) {
    pk0.x = f2bf(pacc[8] * 0.1f);  pk0.y = f2bf(pacc[9] * 0.1f);
    pk0.z = f2bf(pacc[10] * 0.1f); pk0.w = f2bf(pacc[11] * 0.1f);
    pk1.x = f2bf(pacc[12] * 0.1f); pk1.y = f2bf(pacc[13] * 0.1f);
    pk1.z = f2bf(pacc[14] * 0.1f); pk1.w = f2bf(pacc[15] * 0.1f);
    *(ushort4*)(pm + 512 + l * 8) = pk0;
    *(ushort4*)(pm + 512 + l * 8 + 4) = pk1;
  }
}

// =================================================================================
// pv_small v2: one head per block, grid (64,8), 256 thr = 4 waves; wave w does
// nf in {2w, 2w+1} (N=128 as 8 tiles of 16), K=576 (18 MFMA k-steps each).
// attended[b, c, h*128+d] = sum_k Pm[b,h,c,k] * Vt[(b*8+h)*128+d][k].
// =================================================================================
__global__ __launch_bounds__(256) void pv_small_kernel(const u16* __restrict__ Pm,
                                                       const u16* __restrict__ Vt,
                                                       u16* __restrict__ Attd) {
  const int b = blockIdx.x, h = blockIdx.y;
  const int t = threadIdx.x;
  const int w = t >> 6, l = t & 63;
  const int lr = l & 15, lg = l >> 4;
  __shared__ u16 pm[16][584];  // 18688 B; rows 14,15 + chunk 72 zeroed
  for (int i = t; i < 16 * 73; i += 256) {
    const int r = i / 73, ck = i - (i / 73) * 73;
    uint4 v = {0u, 0u, 0u, 0u};
    if (r < 14 && ck < 72)
      v = *(const uint4*)&Pm[((size_t)((b * 8 + h) * 14 + r)) * 576 + ck * 8];
    *(uint4*)&pm[r][ck * 8] = v;
  }
  __syncthreads();
  const u16* vbase = Vt + ((size_t)(b * 8 + h) * 128) * 576;
  f32x4 acc[2] = {};
#pragma unroll 1
  for (int ks = 0; ks < 18; ++ks) {
    const bf16x8 af = *(const bf16x8*)&pm[lr][ks * 32 + lg * 8];
#pragma unroll
    for (int j = 0; j < 2; ++j) {
      const int nf = w * 2 + j;
      const bf16x8 bf = *(const bf16x8*)&vbase[(size_t)(nf * 16 + lr) * 576 + ks * 32 + lg * 8];
      acc[j] = __builtin_amdgcn_mfma_f32_16x16x32_bf16(af, bf, acc[j], 0, 0, 0);
    }
  }
#pragma unroll
  for (int j = 0; j < 2; ++j) {
    const int nf = w * 2 + j;
#pragma unroll
    for (int rg = 0; rg < 4; ++rg) {
      const int cc = lg * 4 + rg;
      if (cc < 14)
        Attd[((size_t)b * 14 + cc) * 1024 + h * 128 + nf * 16 + lr] = f2bf(acc[j][rg]);
    }
  }
}

// ---------------- LN + per-class linear row ----------------
__global__ __launch_bounds__(256) void ln_crossfc_kernel(
    const float* __restrict__ ap, const float* __restrict__ g, const float* __restrict__ bb,
    const float* __restrict__ fw, const float* __restrict__ fb, float* __restrict__ out) {
  const int bc = blockIdx.x;
  const int c = bc % 14;
  const float* x = ap + (size_t)bc * 1024;
  __shared__ float red[4];
  const int t = threadIdx.x;
  float v[4];
  float s = 0.f;
#pragma unroll
  for (int i = 0; i < 4; ++i) { v[i] = x[t + i * 256]; s += v[i]; }
  const float mean = block_sum(s, red) * (1.f / 1024.f);
  float vs = 0.f;
#pragma unroll
  for (int i = 0; i < 4; ++i) { const float d = v[i] - mean; vs += d * d; }
  const float var = block_sum(vs, red) * (1.f / 1024.f);
  const float inv = rsqrtf(var + 1e-5f);
  float acc = 0.f;
#pragma unroll
  for (int i = 0; i < 4; ++i) {
    const int e = t + i * 256;
    const float h = (v[i] - mean) * inv * g[e] + bb[e];
    acc += h * fw[(size_t)c * 1024 + e];
  }
  acc = block_sum(acc, red);
  if (t == 0) out[bc] = acc + fb[c];
}

// ---------------- direct MLP: LN -> relu(W1) -> W2 (2-chain ILP) ----------------
__global__ __launch_bounds__(256) void direct_mlp_kernel(
    const float* __restrict__ vg, const float* __restrict__ g, const float* __restrict__ bb,
    const float* __restrict__ w1, const float* __restrict__ b1,
    const float* __restrict__ w2, const float* __restrict__ b2, float* __restrict__ out) {
  const int b = blockIdx.x;
  __shared__ float red[4];
  __shared__ float gn[1024];
  __shared__ float h1[512];
  const int t = threadIdx.x;
  const float* x = vg + (size_t)b * 1024;
  float v[4];
  float s = 0.f;
#pragma unroll
  for (int i = 0; i < 4; ++i) { v[i] = x[t + i * 256]; s += v[i]; }
  const float mean = block_sum(s, red) * (1.f / 1024.f);
  float vs = 0.f;
#pragma unroll
  for (int i = 0; i < 4; ++i) { const float d = v[i] - mean; vs += d * d; }
  const float var = block_sum(vs, red) * (1.f / 1024.f);
  const float inv = rsqrtf(var + 1e-5f);
#pragma unroll
  for (int i = 0; i < 4; ++i) {
    const int e = t + i * 256;
    gn[e] = (v[i] - mean) * inv * g[e] + bb[e];
  }
  __syncthreads();
  {
    float a0 = b1[t], a1 = b1[t + 256];
    const float4* w0 = (const float4*)(w1 + (size_t)t * 1024);
    const float4* w1p = (const float4*)(w1 + (size_t)(t + 256) * 1024);
    const float4* g4 = (const float4*)gn;
    for (int e = 0; e < 256; ++e) {
      const float4 av = g4[e];
      const float4 u = w0[e], q = w1p[e];
      a0 += av.x * u.x + av.y * u.y + av.z * u.z + av.w * u.w;
      a1 += av.x * q.x + av.y * q.y + av.z * q.z + av.w * q.w;
    }
    h1[t] = fmaxf(a0, 0.f);
    h1[t + 256] = fmaxf(a1, 0.f);
  }
  __syncthreads();
  for (int c = 0; c < 14; ++c) {
    float a = 0.f;
    for (int j = t; j < 512; j += 256) a += h1[j] * w2[(size_t)c * 512 + j];
    a = block_sum(a, red);
    if (t == 0) out[b * 14 + c] = a + b2[c];
  }
}

// ---------------- small f32 linear: 4 rows/block, 4-chain ILP ----------------
// C[r0+rr, j] = A[r0+rr,:] . W[j,:] + bias[j];  grid (rows/4, N/256)
__global__ __launch_bounds__(256) void linear_f32_kernel(
    const float* __restrict__ A, const float* __restrict__ W, const float* __restrict__ bias,
    float* __restrict__ C) {
  const int r0 = blockIdx.x * 4;
  const int j = blockIdx.y * 256 + threadIdx.x;
  __shared__ float a[4][1024];
  for (int e = threadIdx.x; e < 4096; e += 256)
    a[e >> 10][e & 1023] = A[(size_t)(r0 + (e >> 10)) * 1024 + (e & 1023)];
  __syncthreads();
  const float bv = bias ? bias[j] : 0.f;
  float s0 = 0.f, s1 = 0.f, s2 = 0.f, s3 = 0.f;
  const float4* wr = (const float4*)(W + (size_t)j * 1024);
  const float4* a0 = (const float4*)a[0];
  const float4* a1 = (const float4*)a[1];
  const float4* a2 = (const float4*)a[2];
  const float4* a3 = (const float4*)a[3];
  for (int e = 0; e < 256; ++e) {
    const float4 wv = wr[e];
    const float4 v0 = a0[e], v1 = a1[e], v2 = a2[e], v3 = a3[e];
    s0 += v0.x * wv.x + v0.y * wv.y + v0.z * wv.z + v0.w * wv.w;
    s1 += v1.x * wv.x + v1.y * wv.y + v1.z * wv.z + v1.w * wv.w;
    s2 += v2.x * wv.x + v2.y * wv.y + v2.z * wv.z + v2.w * wv.w;
    s3 += v3.x * wv.x + v3.y * wv.y + v3.z * wv.z + v3.w * wv.w;
  }
  C[(size_t)(r0 + 0) * 1024 + j] = s0 + bv;
  C[(size_t)(r0 + 1) * 1024 + j] = s1 + bv;
  C[(size_t)(r0 + 2) * 1024 + j] = s2 + bv;
  C[(size_t)(r0 + 3) * 1024 + j] = s3 + bv;
}

// ---------------- cosine sim / TEMP + combine (merged) ----------------
__global__ __launch_bounds__(256) void sim_combine_kernel(
    const float* __restrict__ co, const float* __restrict__ tp,
    const float* __restrict__ lc, const float* __restrict__ ld,
    float* __restrict__ out) {
  const int b = blockIdx.x;
  const int t = threadIdx.x;
  __shared__ float red[4];
  const float* c = co + (size_t)b * 1024;
  const float* p = tp + (size_t)b * 1024;
  float dd = 0.f, nc = 0.f, nt = 0.f;
  for (int e = t; e < 1024; e += 256) {
    const float cv = c[e], pv = p[e];
    dd += cv * pv; nc += cv * cv; nt += pv * pv;
  }
  dd = block_sum(dd, red);
  nc = block_sum(nc, red);
  nt = block_sum(nt, red);
  const float sim = dd / (fmaxf(sqrtf(nc), 1e-12f) * fmaxf(sqrtf(nt), 1e-12f)) / 0.1f;
  if (t < 14) {
    const int i = b * 14 + t;
    const float sup = 0.5f * (lc[i] + ld[i]);
    out[i] = sim;
    out[896 + i] = sup;
    out[1792 + i] = 0.5f * (sup + sim);
  }
}

// ---------------- workspace layout ----------------
static constexpr size_t OFF_X    = 0;
static constexpr size_t OFF_K    = OFF_X + 75497472;   // Kb; later Pm (8.3MB)
static constexpr size_t OFF_SP   = OFF_K + 75759616;   // V-fallback / S
static constexpr size_t OFF_WIN  = OFF_SP + 85082112;
static constexpr size_t OFF_WOUT = OFF_WIN + 6291456;
static constexpr size_t OFF_ASP  = OFF_WOUT + 2097152;
static constexpr size_t OFF_QASP = OFF_ASP + 524288;
static constexpr size_t OFF_ATT  = OFF_QASP + 524288;
static constexpr size_t OFF_APRJ = OFF_ATT + 1835008;
static constexpr size_t OFF_TP   = OFF_APRJ + 3670016;
static constexpr size_t OFF_CV   = OFF_TP + 262144;
static constexpr size_t OFF_CO   = OFF_CV + 262144;
static constexpr size_t OFF_SIM  = OFF_CO + 262144;
static constexpr size_t OFF_LC   = OFF_SIM + 4096;
static constexpr size_t OFF_LD   = OFF_LC + 4096;
static constexpr size_t WS_SMALL = OFF_LD + 4096;
static constexpr size_t OFF_VT   = WS_SMALL;
static constexpr size_t WS_BIG   = OFF_VT + 75497472;

extern "C" void kernel_launch(void* const* d_in, const int* in_sizes, int n_in,
                              void* d_out, int out_size, void* d_ws, size_t ws_size,
                              hipStream_t stream) {
  (void)in_sizes; (void)n_in; (void)out_size;
  const float* vision_features = (const float*)d_in[0];
  const float* text_embeddings = (const float*)d_in[1];
  const float* vision_global   = (const float*)d_in[2];
  const float* aspect_queries  = (const float*)d_in[3];
  const float* ch_in_w  = (const float*)d_in[4];
  const float* ch_in_b  = (const float*)d_in[5];
  const float* ch_out_w = (const float*)d_in[6];
  const float* ch_out_b = (const float*)d_in[7];
  const float* tp_w = (const float*)d_in[8];
  const float* tp_b = (const float*)d_in[9];
  const float* ca_in_w  = (const float*)d_in[10];
  const float* ca_in_b  = (const float*)d_in[11];
  const float* ca_out_w = (const float*)d_in[12];
  const float* ca_out_b = (const float*)d_in[13];
  const float* cross_ln_g = (const float*)d_in[14];
  const float* cross_ln_b = (const float*)d_in[15];
  const float* cross_fc_w = (const float*)d_in[16];
  const float* cross_fc_b = (const float*)d_in[17];
  const float* dir_ln_g = (const float*)d_in[18];
  const float* dir_ln_b = (const float*)d_in[19];
  const float* dir_w1 = (const float*)d_in[20];
  const float* dir_b1 = (const float*)d_in[21];
  const float* dir_w2 = (const float*)d_in[22];
  const float* dir_b2 = (const float*)d_in[23];

  if (ws_size < WS_SMALL) {
    fprintf(stderr, "kernel_launch: ws too small: %zu < %zu\n", ws_size, WS_SMALL);
    return;
  }
  const bool big = (ws_size >= WS_BIG);

  char* ws = (char*)d_ws;
  u16* Xb      = (u16*)(ws + OFF_X);
  u16* Kb      = (u16*)(ws + OFF_K);
  u16* Pm      = (u16*)(ws + OFF_K);   // after S-GEMM, Kb is dead
  u16* Vb      = (u16*)(ws + OFF_SP);
  u16* SP      = (u16*)(ws + OFF_SP);
  u16* Vt      = big ? (u16*)(ws + OFF_VT) : (u16*)(ws + OFF_X);
  u16* Win     = (u16*)(ws + OFF_WIN);
  u16* Wout    = (u16*)(ws + OFF_WOUT);
  u16* Asp     = (u16*)(ws + OFF_ASP);
  u16* Qasp    = (u16*)(ws + OFF_QASP);
  u16* Attd    = (u16*)(ws + OFF_ATT);
  float* Aprj  = (float*)(ws + OFF_APRJ);
  float* Tp    = (float*)(ws + OFF_TP);
  float* Cv2   = (float*)(ws + OFF_CV);
  float* Co    = (float*)(ws + OFF_CO);
  float* Lc    = (float*)(ws + OFF_LC);
  float* Ld    = (float*)(ws + OFF_LD);
  float* attnOut = (float*)d_out + 2688;

  // ---- converts to bf16 ----
  cvt4_kernel<<<3107, 256, 0, stream>>>(vision_features, Xb, ca_in_w, Win,
                                        ca_out_w, Wout, aspect_queries, Asp);

  // ---- fused K+V+Q projections, 256x256 4-phase pipeline ----
  if (big) {
    gemm_kvq_kernel<1><<<dim3(1156), 512, 0, stream>>>(
        Xb, Win + 1024 * 1024, Asp, Win, Kb, nullptr, Vt, Qasp,
        ca_in_b + 1024, ca_in_b);
  } else {
    gemm_kvq_kernel<0><<<dim3(1156), 512, 0, stream>>>(
        Xb, Win + 1024 * 1024, Asp, Win, Kb, Vb, nullptr, Qasp,
        ca_in_b + 1024, ca_in_b);
    transpose_v_kernel<<<dim3(9, 16, 64), 256, 0, stream>>>(Vb, Vt);
  }

  // ---- S = Q K^T / sqrt(128): KT=2, grid (5 n-tiles, 512 bh), bf16 out ----
  gemm_big_kernel<0><<<dim3(5, 512), 512, 0, stream>>>(
      Qasp, Kb, SP, nullptr, 0.08838834764831845f,
      2, 5, 140, 576, 1024, 1024, 576, 8,
      0L, 128L, 589824L, 128L, 663552L, 82944L);

  // ---- softmax (vectorized) + head-mean attnOut + query-mean Pm ----
  softmax_pm_kernel<<<dim3(64, 14), 512, 0, stream>>>(SP, attnOut, Pm);

  // ---- attended = Pm . V  (one head per block) ----
  pv_small_kernel<<<dim3(64, 8), 256, 0, stream>>>(Pm, Vt, Attd);

  // ---- out projection: KT=16, grid (4x8 tiles), f32 out ----
  gemm_big_kernel<1><<<dim3(32, 1), 512, 0, stream>>>(
      Attd, Wout, Aprj, ca_out_b, 1.0f,
      16, 8, 896, 1024, 1024, 1024, 1024, 1,
      0L, 0L, 0L, 0L, 0L, 0L);

  // ---- LN + per-class fc ----
  ln_crossfc_kernel<<<896, 256, 0, stream>>>(Aprj, cross_ln_g, cross_ln_b,
                                             cross_fc_w, cross_fc_b, Lc);

  // ---- direct MLP ----
  direct_mlp_kernel<<<64, 256, 0, stream>>>(vision_global, dir_ln_g, dir_ln_b,
                                            dir_w1, dir_b1, dir_w2, dir_b2, Ld);

  // ---- contrastive chain (f32; 1-key attention is identity) ----
  linear_f32_kernel<<<dim3(16, 4), 256, 0, stream>>>(text_embeddings, tp_w, tp_b, Tp);
  linear_f32_kernel<<<dim3(16, 4), 256, 0, stream>>>(Tp, ch_in_w + 2048 * 1024, ch_in_b + 2048, Cv2);
  linear_f32_kernel<<<dim3(16, 4), 256, 0, stream>>>(Cv2, ch_out_w, ch_out_b, Co);

  // ---- sim + combine (merged) ----
  sim_combine_kernel<<<64, 256, 0, stream>>>(Co, Tp, Lc, Ld, (float*)d_out);
}

// Round 9
// 635.455 us; speedup vs baseline: 1.0937x; 1.0937x over previous
//
#include <hip/hip_runtime.h>
#include <cstdio>
#include <cstdint>

using u16 = unsigned short;
typedef __bf16 bf16x8 __attribute__((ext_vector_type(8)));
typedef unsigned short ushort8 __attribute__((ext_vector_type(8)));
typedef float f32x4 __attribute__((ext_vector_type(4)));

#define GLOBAL_AS __attribute__((address_space(1)))
#define LDS_AS __attribute__((address_space(3)))

__device__ __forceinline__ float bf2f(u16 h) {
  return __uint_as_float(((unsigned)h) << 16);
}
__device__ __forceinline__ u16 f2bf(float f) {
  unsigned u = __float_as_uint(f);
  u += 0x7FFFu + ((u >> 16) & 1u);
  return (u16)(u >> 16);
}

__device__ __forceinline__ void async_copy16(void* lds, const void* g) {
  __builtin_amdgcn_global_load_lds((const GLOBAL_AS unsigned int*)g,
                                   (LDS_AS unsigned int*)lds, 16, 0, 0);
}

// ---------------- block reduction helpers (blockDim = 256) ----------------
__device__ __forceinline__ float block_sum(float v, float* red) {
#pragma unroll
  for (int o = 32; o >= 1; o >>= 1) v += __shfl_xor(v, o);
  __syncthreads();
  if ((threadIdx.x & 63) == 0) red[threadIdx.x >> 6] = v;
  __syncthreads();
  return red[0] + red[1] + red[2] + red[3];
}

// ---------------- merged f32 -> bf16 converts (4 ranges, 1 launch) ----------------
__global__ __launch_bounds__(256) void cvt4_kernel(
    const float* __restrict__ s0, u16* __restrict__ d0,
    const float* __restrict__ s1, u16* __restrict__ d1,
    const float* __restrict__ s2, u16* __restrict__ d2,
    const float* __restrict__ s3, u16* __restrict__ d3) {
  const float* s; u16* d; long n; long b0; long nb;
  const int b = blockIdx.x;
  if (b < 2048)      { s = s0; d = d0; n = 37748736L; b0 = b;        nb = 2048; }
  else if (b < 2816) { s = s1; d = d1; n = 3145728L;  b0 = b - 2048; nb = 768; }
  else if (b < 3072) { s = s2; d = d2; n = 1048576L;  b0 = b - 2816; nb = 256; }
  else               { s = s3; d = d3; n = 143360L;   b0 = b - 3072; nb = 35; }
  long i = (b0 * 256 + threadIdx.x) * 4;
  const long stride = nb * 1024;
  for (; i < n; i += stride) {
    float4 v = *(const float4*)(s + i);
    ushort4 o;
    o.x = f2bf(v.x); o.y = f2bf(v.y); o.z = f2bf(v.z); o.w = f2bf(v.w);
    *(ushort4*)(d + i) = o;
  }
}

// =================================================================================
// Fused K+V+Q projection GEMM — 256x256 8-wave 4-phase schedule (round-6 proven).
// =================================================================================
template <int VTD>
__global__ __launch_bounds__(512, 2) void gemm_kvq_kernel(
    const u16* __restrict__ A, const u16* __restrict__ Bkv,
    const u16* __restrict__ Aq, const u16* __restrict__ Bq,
    u16* __restrict__ Ck, u16* __restrict__ Cvp, u16* __restrict__ Vt,
    u16* __restrict__ Cq,
    const float* __restrict__ bias, const float* __restrict__ biasq) {
  __shared__ char smem[131072];  // dbuf d: A at d*65536, B at d*65536+32768
  const int bid = blockIdx.x;
  const int t = threadIdx.x;
  const int wid = t >> 6, l = t & 63;
  const int wm = wid >> 2, wn = wid & 3;
  const int lr = l & 15, lg = l >> 4, lr7 = lr & 7;

  int mt = 0, nt = 0, qb = -1;
  const u16* Abase; const u16* Bbase; const float* bias_b;
  if (bid < 1152) {
    const int wgid = (bid & 7) * 144 + (bid >> 3);  // XCD swizzle (1152 = 8*144)
    mt = wgid >> 3; nt = wgid & 7;                  // nt fastest: A-panel L2 reuse
    Abase = A + (size_t)mt * 256 * 1024;
    Bbase = Bkv + (size_t)nt * 256 * 1024;
    bias_b = bias + nt * 256;
  } else {
    qb = bid - 1152;  // 0..3
    Abase = Aq;
    Bbase = Bq + (size_t)qb * 256 * 1024;
    bias_b = biasq + qb * 256;
  }

  const int srow = t >> 3;
  const int scx = (t & 7) ^ (srow & 7);
  const char* Asrc = (const char*)Abase + (size_t)srow * 2048 + (scx << 4);
  const char* Bsrc = (const char*)Bbase + (size_t)srow * 2048 + (scx << 4);
  const int wb = wid << 10;

  f32x4 acc[8][4] = {};

#define SA(d, r, kt) async_copy16(smem + (d)*65536 + (r)*8192 + wb, \
                                  Asrc + (size_t)(r)*131072 + (size_t)(kt)*128)
#define SB(d, r, kt) async_copy16(smem + (d)*65536 + 32768 + (r)*8192 + wb, \
                                  Bsrc + (size_t)(r)*131072 + (size_t)(kt)*128)

#define RA(d, half)                                                          \
  _Pragma("unroll")                                                          \
  for (int i = 0; i < 4; ++i) {                                              \
    const int row = wm * 128 + ((half)*4 + i) * 16 + lr;                     \
    af[i][0] = *(const bf16x8*)(smem + (d)*65536 + (row << 7) + ((lg ^ lr7) << 4));       \
    af[i][1] = *(const bf16x8*)(smem + (d)*65536 + (row << 7) + (((4 | lg) ^ lr7) << 4)); \
  }

#define RB(d, half)                                                          \
  _Pragma("unroll")                                                          \
  for (int j = 0; j < 2; ++j) {                                              \
    const int row = wn * 64 + ((half)*2 + j) * 16 + lr;                      \
    bfr[j][0] = *(const bf16x8*)(smem + (d)*65536 + 32768 + (row << 7) + ((lg ^ lr7) << 4));       \
    bfr[j][1] = *(const bf16x8*)(smem + (d)*65536 + 32768 + (row << 7) + (((4 | lg) ^ lr7) << 4)); \
  }

#define MM(mh, nh)                                                           \
  __builtin_amdgcn_s_setprio(1);                                             \
  _Pragma("unroll")                                                          \
  for (int ks = 0; ks < 2; ++ks)                                             \
    _Pragma("unroll")                                                        \
    for (int i = 0; i < 4; ++i)                                              \
      _Pragma("unroll")                                                      \
      for (int j = 0; j < 2; ++j)                                            \
        acc[(mh)*4 + i][(nh)*2 + j] = __builtin_amdgcn_mfma_f32_16x16x32_bf16( \
            af[i][ks], bfr[j][ks], acc[(mh)*4 + i][(nh)*2 + j], 0, 0, 0);    \
  __builtin_amdgcn_s_setprio(0);

  SA(0, 0, 0); SA(0, 1, 0); SA(0, 2, 0); SA(0, 3, 0);
  SB(0, 0, 0); SB(0, 1, 0); SB(0, 2, 0); SB(0, 3, 0);
  SA(1, 0, 1); SA(1, 2, 1);
  asm volatile("s_waitcnt vmcnt(2)" ::: "memory");
  __builtin_amdgcn_s_barrier();
  asm volatile("" ::: "memory");

#pragma unroll 1
  for (int kt = 0; kt < 16; ++kt) {
    const int cur = kt & 1, nxt = cur ^ 1;
    const bool pf1 = (kt < 15), pf2 = (kt < 14);
    bf16x8 af[4][2], bfr[2][2];
    RA(cur, 0);
    RB(cur, 0);
    if (pf1) { SB(nxt, 0, kt + 1); SB(nxt, 1, kt + 1); }
    __builtin_amdgcn_s_barrier();
    asm volatile("s_waitcnt lgkmcnt(0)" ::: "memory");
    MM(0, 0);
    __builtin_amdgcn_s_barrier();
    RB(cur, 1);
    if (pf1) { SB(nxt, 2, kt + 1); SB(nxt, 3, kt + 1); }
    __builtin_amdgcn_s_barrier();
    asm volatile("s_waitcnt lgkmcnt(0)" ::: "memory");
    MM(0, 1);
    if (pf1) asm volatile("s_waitcnt vmcnt(6)" ::: "memory");
    __builtin_amdgcn_s_barrier();
    RA(cur, 1);
    if (pf1) { SA(nxt, 1, kt + 1); SA(nxt, 3, kt + 1); }
    __builtin_amdgcn_s_barrier();
    asm volatile("s_waitcnt lgkmcnt(0)" ::: "memory");
    MM(1, 1);
    __builtin_amdgcn_s_barrier();
    RB(cur, 0);
    if (pf2) { SA(cur, 0, kt + 2); SA(cur, 2, kt + 2); }
    __builtin_amdgcn_s_barrier();
    asm volatile("s_waitcnt lgkmcnt(0)" ::: "memory");
    MM(1, 0);
    if (pf2)      asm volatile("s_waitcnt vmcnt(4)" ::: "memory");
    else if (pf1) asm volatile("s_waitcnt vmcnt(0)" ::: "memory");
    __builtin_amdgcn_s_barrier();
  }
#undef SA
#undef SB
#undef RA
#undef RB
#undef MM

  // ---------------- epilogue ----------------
  if (VTD && qb < 0 && nt >= 4) {
    u16* T = (u16*)smem;
    const int vc2 = t >> 1, seg = t & 1;
    const int vglob = (nt - 4) * 256 + vc2;
    const int h2 = vglob >> 7, d2 = vglob & 127;
#pragma unroll 1
    for (int mh = 0; mh < 2; ++mh) {
      __syncthreads();
      if (wm == mh) {
#pragma unroll
        for (int ni = 0; ni < 4; ++ni) {
          const int vc = wn * 64 + ni * 16 + lr;
          const float bv = bias_b[vc];
#pragma unroll
          for (int mi = 0; mi < 8; ++mi) {
            const int ml = mi * 16 + lg * 4;
            ushort4 pk;
            pk.x = f2bf(acc[mi][ni][0] + bv);
            pk.y = f2bf(acc[mi][ni][1] + bv);
            pk.z = f2bf(acc[mi][ni][2] + bv);
            pk.w = f2bf(acc[mi][ni][3] + bv);
            *(ushort4*)(T + (size_t)vc * 136 + ml) = pk;
          }
        }
      }
      __syncthreads();
      const int mg0 = mt * 256 + mh * 128 + seg * 64;
      const int bb = (unsigned)mg0 / 576u;
      const int k0 = mg0 - bb * 576;
      u16* dst = Vt + ((size_t)(bb * 8 + h2) * 128 + d2) * 576 + k0;
      const u16* src = T + (size_t)vc2 * 136 + seg * 64;
#pragma unroll
      for (int i2 = 0; i2 < 8; ++i2)
        *(uint4*)(dst + i2 * 8) = *(const uint4*)(src + i2 * 8);
    }
  } else {
    u16* D; int cb0;
    if (qb >= 0)      { D = Cq;  cb0 = qb * 256; }
    else if (nt < 4)  { D = Ck;  cb0 = nt * 256; }
    else              { D = Cvp; cb0 = (nt - 4) * 256; }
#pragma unroll
    for (int ni = 0; ni < 4; ++ni) {
      const int nc = wn * 64 + ni * 16 + lr;
      const float bv = bias_b[nc];
      const int col = cb0 + nc;
#pragma unroll
      for (int mi = 0; mi < 8; ++mi) {
#pragma unroll
        for (int rg = 0; rg < 4; ++rg) {
          const size_t m = (size_t)mt * 256 + wm * 128 + mi * 16 + lg * 4 + rg;
          D[m * 1024 + col] = f2bf(acc[mi][ni][rg] + bv);
        }
      }
    }
  }
}

// =================================================================================
// Generic deep-pipelined batched GEMM (round-2 proven loop; used for S, out-proj)
// =================================================================================
template <int OUTF32>
__global__ __launch_bounds__(512, 2) void gemm_big_kernel(
    const u16* __restrict__ A, const u16* __restrict__ B, void* __restrict__ Cv,
    const float* __restrict__ bias, float scale,
    int KT, int ntx, int Mlim, int Nlim,
    long lda, long ldb, long ldc, int bdiv,
    long sA0, long sA1, long sB0, long sB1, long sC0, long sC1) {
  __shared__ u16 lds[3][24576];
  const int bid = blockIdx.x;
  const int bh = blockIdx.y;
  const int bb0 = bh / bdiv, bb1 = bh % bdiv;
  const int mt = bid / ntx, nt = bid % ntx;
  const int t = threadIdx.x;
  const int wid = t >> 6, l = t & 63;
  const int wr = wid >> 1, wc = wid & 1;
  const int lr = l & 15, lg = l >> 4, lr7 = lr & 7;

  const long ldab = lda * 2, ldbb = ldb * 2;
  const u16* Abase = A + (long)bb0 * sA0 + (long)bb1 * sA1 + (long)mt * 256 * lda;
  const u16* Bbase = B + (long)bb0 * sB0 + (long)bb1 * sB1 + (long)nt * 128 * ldb;

  const int srow = t >> 3;
  const int scx = (t & 7) ^ (srow & 7);
  const char* Asrc = (const char*)Abase + (long)srow * ldab + (scx << 4);
  const char* Bsrc = (const char*)Bbase + (long)srow * ldbb + (scx << 4);
  const int wbA = wid << 10;

  char* b0 = (char*)lds[0];
  char* b1 = (char*)lds[1];
  char* b2 = (char*)lds[2];

  f32x4 acc[4][4] = {};

#define STAGE3G(dst, kt, part)                                              \
  {                                                                         \
    const long ko = (long)(kt) * 128;                                       \
    if ((part) == 0) {                                                      \
      async_copy16((dst) + wbA,          Asrc + ko);                        \
      async_copy16((dst) + 8192 + wbA,   Asrc + 64 * ldab + ko);            \
      async_copy16((dst) + 16384 + wbA,  Asrc + 128 * ldab + ko);           \
    } else {                                                                \
      async_copy16((dst) + 24576 + wbA,  Asrc + 192 * ldab + ko);           \
      async_copy16((dst) + 32768 + wbA,  Bsrc + ko);                        \
      async_copy16((dst) + 40960 + wbA,  Bsrc + 64 * ldbb + ko);            \
    }                                                                       \
  }

#define COMPUTE_KS(p, KS)                                                   \
  {                                                                         \
    const int ccol = (((KS) << 2) | lg) ^ lr7;                              \
    const char* pA = (p) + (((wr << 6) + lr) << 7) + (ccol << 4);           \
    const char* pB = (p) + 32768 + (((wc << 6) + lr) << 7) + (ccol << 4);   \
    bf16x8 af[4], bfr[4];                                                   \
    _Pragma("unroll")                                                       \
    for (int i = 0; i < 4; ++i) {                                           \
      af[i]  = *(const bf16x8*)(pA + i * 2048);                             \
      bfr[i] = *(const bf16x8*)(pB + i * 2048);                             \
    }                                                                       \
    __builtin_amdgcn_s_setprio(1);                                          \
    _Pragma("unroll")                                                       \
    for (int mi = 0; mi < 4; ++mi)                                          \
      _Pragma("unroll")                                                     \
      for (int ni = 0; ni < 4; ++ni)                                        \
        acc[mi][ni] = __builtin_amdgcn_mfma_f32_16x16x32_bf16(              \
            af[mi], bfr[ni], acc[mi][ni], 0, 0, 0);                         \
    __builtin_amdgcn_s_setprio(0);                                          \
  }

  STAGE3G(b0, 0, 0); STAGE3G(b0, 0, 1);
  STAGE3G(b1, 1, 0); STAGE3G(b1, 1, 1);
  asm volatile("s_waitcnt vmcnt(6)" ::: "memory");
  __builtin_amdgcn_s_barrier();
  asm volatile("" ::: "memory");

  char* p0 = b0; char* p1 = b1; char* p2 = b2;
#pragma unroll 1
  for (int kt = 0; kt < KT; ++kt) {
    const bool pf = (kt < KT - 2);
    if (pf) STAGE3G(p2, kt + 2, 0);
    COMPUTE_KS(p0, 0);
    if (pf) STAGE3G(p2, kt + 2, 1);
    COMPUTE_KS(p0, 1);
    if (kt < KT - 1) {
      if (pf) asm volatile("s_waitcnt vmcnt(6)" ::: "memory");
      else    asm volatile("s_waitcnt vmcnt(0)" ::: "memory");
      __builtin_amdgcn_s_barrier();
      asm volatile("" ::: "memory");
    }
    char* tmp = p0; p0 = p1; p1 = p2; p2 = tmp;
  }
#undef STAGE3G
#undef COMPUTE_KS

  const long cBase = (long)bb0 * sC0 + (long)bb1 * sC1;
  const int mr0 = mt * 256 + wr * 64 + lg * 4;
  const int nc0 = nt * 128 + wc * 64 + lr;
#pragma unroll
  for (int ni = 0; ni < 4; ++ni) {
    const int n = nc0 + ni * 16;
    if (n >= Nlim) continue;
    const float bv = bias ? bias[n] : 0.0f;
#pragma unroll
    for (int mi = 0; mi < 4; ++mi) {
#pragma unroll
      for (int rg = 0; rg < 4; ++rg) {
        const int m = mr0 + mi * 16 + rg;
        if (m >= Mlim) continue;
        const float v = acc[mi][ni][rg] * scale + bv;
        if (OUTF32) ((float*)Cv)[cBase + (long)m * ldc + n] = v;
        else        ((u16*)Cv)[cBase + (long)m * ldc + n] = f2bf(v);
      }
    }
  }
}

// ---------------- V transpose (fallback path only) ----------------
__global__ __launch_bounds__(256) void transpose_v_kernel(const u16* __restrict__ V,
                                                          u16* __restrict__ Vt) {
  __shared__ u16 tile[64][65];
  const int k0 = blockIdx.x * 64;
  const int c0 = blockIdx.y * 64;
  const int b = blockIdx.z;
  const int t = threadIdx.x;
  const int tx = t & 15, ty = t >> 4;
  const u16* Vb = V + (size_t)(b * 576) * 1024;
#pragma unroll
  for (int i = 0; i < 4; ++i) {
    const int k = ty + i * 16;
    const u16* src = Vb + (size_t)(k0 + k) * 1024 + c0 + tx * 4;
    ushort2 v01 = *(const ushort2*)src;
    ushort2 v23 = *(const ushort2*)(src + 2);
    tile[k][tx * 4 + 0] = v01.x; tile[k][tx * 4 + 1] = v01.y;
    tile[k][tx * 4 + 2] = v23.x; tile[k][tx * 4 + 3] = v23.y;
  }
  __syncthreads();
  const int h = c0 >> 7, d0 = c0 & 127;
  u16* VtB = Vt + ((size_t)(b * 8 + h) * 128 + d0) * 576 + k0;
#pragma unroll
  for (int i = 0; i < 4; ++i) {
    const int d = ty + i * 16;
    u16* dst = VtB + (size_t)d * 576 + tx * 4;
    ushort2 a, bb2;
    a.x = tile[tx * 4 + 0][d]; a.y = tile[tx * 4 + 1][d];
    bb2.x = tile[tx * 4 + 2][d]; bb2.y = tile[tx * 4 + 3][d];
    *(ushort2*)dst = a; *(ushort2*)(dst + 2) = bb2;
  }
}

// =================================================================================
// softmax_pm: vectorized (G13). Block (b,c)=64x14, 512 thr = 8 waves = 8 heads.
// =================================================================================
__global__ __launch_bounds__(512) void softmax_pm_kernel(const u16* __restrict__ SP,
                                                         float* __restrict__ attnOut,
                                                         u16* __restrict__ Pm) {
  const int b = blockIdx.x, c = blockIdx.y;
  const int h = threadIdx.x >> 6, l = threadIdx.x & 63;
  const bool ex = (l < 8);
  __shared__ float pl[8][72][9];  // 20736 B
  float pacc[16] = {};
#pragma unroll 1
  for (int qq = 0; qq < 10; ++qq) {
    const u16* row = SP + ((size_t)((b * 8 + h) * 144 + c * 10 + qq)) * 576;
    ushort8 v0 = *(const ushort8*)(row + l * 8);
    ushort8 v1 = {0, 0, 0, 0, 0, 0, 0, 0};
    if (ex) v1 = *(const ushort8*)(row + 512 + l * 8);
    float x[16];
#pragma unroll
    for (int i = 0; i < 8; ++i) { x[i] = bf2f(v0[i]); x[8 + i] = bf2f(v1[i]); }
    float m = x[0];
#pragma unroll
    for (int i = 1; i < 8; ++i) m = fmaxf(m, x[i]);
    if (ex)
#pragma unroll
      for (int i = 8; i < 16; ++i) m = fmaxf(m, x[i]);
#pragma unroll
    for (int o = 32; o >= 1; o >>= 1) m = fmaxf(m, __shfl_xor(m, o));
    float e[16], s = 0.f;
#pragma unroll
    for (int i = 0; i < 8; ++i) { e[i] = expf(x[i] - m); s += e[i]; }
    if (ex) {
#pragma unroll
      for (int i = 8; i < 16; ++i) { e[i] = expf(x[i] - m); s += e[i]; }
    }
#pragma unroll
    for (int o = 32; o >= 1; o >>= 1) s += __shfl_xor(s, o);
    const float inv = 1.f / s;
#pragma unroll
    for (int i = 0; i < 8; ++i) {
      const float p = e[i] * inv;
      pacc[i] += p;
      pl[h][l][i] = p;
    }
    if (ex) {
#pragma unroll
      for (int i = 0; i < 8; ++i) {
        const float p = e[8 + i] * inv;
        pacc[8 + i] += p;
        pl[h][64 + l][i] = p;
      }
    }
    __syncthreads();
    float* out = attnOut + ((size_t)(b * 140 + c * 10 + qq)) * 576;
    {
      const int j = threadIdx.x;
      float a = 0.f;
#pragma unroll
      for (int hh = 0; hh < 8; ++hh) a += pl[hh][j >> 3][j & 7];
      out[j] = a * 0.125f;
      if (j < 64) {
        const int j2 = j + 512;
        float a2 = 0.f;
#pragma unroll
        for (int hh = 0; hh < 8; ++hh) a2 += pl[hh][j2 >> 3][j2 & 7];
        out[j2] = a2 * 0.125f;
      }
    }
    __syncthreads();  // pl reused next qq
  }
  // query-mean -> Pm (bf16), vectorized 16B stores
  u16* pm = Pm + ((size_t)((b * 8 + h) * 14 + c)) * 576;
  ushort4 pk0, pk1;
  pk0.x = f2bf(pacc[0] * 0.1f); pk0.y = f2bf(pacc[1] * 0.1f);
  pk0.z = f2bf(pacc[2] * 0.1f); pk0.w = f2bf(pacc[3] * 0.1f);
  pk1.x = f2bf(pacc[4] * 0.1f); pk1.y = f2bf(pacc[5] * 0.1f);
  pk1.z = f2bf(pacc[6] * 0.1f); pk1.w = f2bf(pacc[7] * 0.1f);
  *(ushort4*)(pm + l * 8) = pk0;
  *(ushort4*)(pm + l * 8 + 4) = pk1;
  if (ex) {
    pk0.x = f2bf(pacc[8] * 0.1f);  pk0.y = f2bf(pacc[9] * 0.1f);
    pk0.z = f2bf(pacc[10] * 0.1f); pk0.w = f2bf(pacc[11] * 0.1f);
    pk1.x = f2bf(pacc[12] * 0.1f); pk1.y = f2bf(pacc[13] * 0.1f);
    pk1.z = f2bf(pacc[14] * 0.1f); pk1.w = f2bf(pacc[15] * 0.1f);
    *(ushort4*)(pm + 512 + l * 8) = pk0;
    *(ushort4*)(pm + 512 + l * 8 + 4) = pk1;
  }
}

// =================================================================================
// pv_small v2: one head per block, grid (64,8), 256 thr = 4 waves.
// =================================================================================
__global__ __launch_bounds__(256) void pv_small_kernel(const u16* __restrict__ Pm,
                                                       const u16* __restrict__ Vt,
                                                       u16* __restrict__ Attd) {
  const int b = blockIdx.x, h = blockIdx.y;
  const int t = threadIdx.x;
  const int w = t >> 6, l = t & 63;
  const int lr = l & 15, lg = l >> 4;
  __shared__ u16 pm[16][584];  // 18688 B; rows 14,15 + chunk 72 zeroed
  for (int i = t; i < 16 * 73; i += 256) {
    const int r = i / 73, ck = i - (i / 73) * 73;
    uint4 v = {0u, 0u, 0u, 0u};
    if (r < 14 && ck < 72)
      v = *(const uint4*)&Pm[((size_t)((b * 8 + h) * 14 + r)) * 576 + ck * 8];
    *(uint4*)&pm[r][ck * 8] = v;
  }
  __syncthreads();
  const u16* vbase = Vt + ((size_t)(b * 8 + h) * 128) * 576;
  f32x4 acc[2] = {};
#pragma unroll 1
  for (int ks = 0; ks < 18; ++ks) {
    const bf16x8 af = *(const bf16x8*)&pm[lr][ks * 32 + lg * 8];
#pragma unroll
    for (int j = 0; j < 2; ++j) {
      const int nf = w * 2 + j;
      const bf16x8 bf = *(const bf16x8*)&vbase[(size_t)(nf * 16 + lr) * 576 + ks * 32 + lg * 8];
      acc[j] = __builtin_amdgcn_mfma_f32_16x16x32_bf16(af, bf, acc[j], 0, 0, 0);
    }
  }
#pragma unroll
  for (int j = 0; j < 2; ++j) {
    const int nf = w * 2 + j;
#pragma unroll
    for (int rg = 0; rg < 4; ++rg) {
      const int cc = lg * 4 + rg;
      if (cc < 14)
        Attd[((size_t)b * 14 + cc) * 1024 + h * 128 + nf * 16 + lr] = f2bf(acc[j][rg]);
    }
  }
}

// ---------------- LN + per-class linear row ----------------
__global__ __launch_bounds__(256) void ln_crossfc_kernel(
    const float* __restrict__ ap, const float* __restrict__ g, const float* __restrict__ bb,
    const float* __restrict__ fw, const float* __restrict__ fb, float* __restrict__ out) {
  const int bc = blockIdx.x;
  const int c = bc % 14;
  const float* x = ap + (size_t)bc * 1024;
  __shared__ float red[4];
  const int t = threadIdx.x;
  float v[4];
  float s = 0.f;
#pragma unroll
  for (int i = 0; i < 4; ++i) { v[i] = x[t + i * 256]; s += v[i]; }
  const float mean = block_sum(s, red) * (1.f / 1024.f);
  float vs = 0.f;
#pragma unroll
  for (int i = 0; i < 4; ++i) { const float d = v[i] - mean; vs += d * d; }
  const float var = block_sum(vs, red) * (1.f / 1024.f);
  const float inv = rsqrtf(var + 1e-5f);
  float acc = 0.f;
#pragma unroll
  for (int i = 0; i < 4; ++i) {
    const int e = t + i * 256;
    const float h = (v[i] - mean) * inv * g[e] + bb[e];
    acc += h * fw[(size_t)c * 1024 + e];
  }
  acc = block_sum(acc, red);
  if (t == 0) out[bc] = acc + fb[c];
}

// ---------------- direct MLP: LN -> relu(W1) -> W2 (2-chain ILP) ----------------
__global__ __launch_bounds__(256) void direct_mlp_kernel(
    const float* __restrict__ vg, const float* __restrict__ g, const float* __restrict__ bb,
    const float* __restrict__ w1, const float* __restrict__ b1,
    const float* __restrict__ w2, const float* __restrict__ b2, float* __restrict__ out) {
  const int b = blockIdx.x;
  __shared__ float red[4];
  __shared__ float gn[1024];
  __shared__ float h1[512];
  const int t = threadIdx.x;
  const float* x = vg + (size_t)b * 1024;
  float v[4];
  float s = 0.f;
#pragma unroll
  for (int i = 0; i < 4; ++i) { v[i] = x[t + i * 256]; s += v[i]; }
  const float mean = block_sum(s, red) * (1.f / 1024.f);
  float vs = 0.f;
#pragma unroll
  for (int i = 0; i < 4; ++i) { const float d = v[i] - mean; vs += d * d; }
  const float var = block_sum(vs, red) * (1.f / 1024.f);
  const float inv = rsqrtf(var + 1e-5f);
#pragma unroll
  for (int i = 0; i < 4; ++i) {
    const int e = t + i * 256;
    gn[e] = (v[i] - mean) * inv * g[e] + bb[e];
  }
  __syncthreads();
  {
    float a0 = b1[t], a1 = b1[t + 256];
    const float4* w0 = (const float4*)(w1 + (size_t)t * 1024);
    const float4* w1p = (const float4*)(w1 + (size_t)(t + 256) * 1024);
    const float4* g4 = (const float4*)gn;
    for (int e = 0; e < 256; ++e) {
      const float4 av = g4[e];
      const float4 u = w0[e], q = w1p[e];
      a0 += av.x * u.x + av.y * u.y + av.z * u.z + av.w * u.w;
      a1 += av.x * q.x + av.y * q.y + av.z * q.z + av.w * q.w;
    }
    h1[t] = fmaxf(a0, 0.f);
    h1[t + 256] = fmaxf(a1, 0.f);
  }
  __syncthreads();
  for (int c = 0; c < 14; ++c) {
    float a = 0.f;
    for (int j = t; j < 512; j += 256) a += h1[j] * w2[(size_t)c * 512 + j];
    a = block_sum(a, red);
    if (t == 0) out[b * 14 + c] = a + b2[c];
  }
}

// ---------------- small f32 linear (round-7 proven: 1 row/block, grid (64,4)) ----------------
__global__ __launch_bounds__(256) void linear_f32_kernel(
    const float* __restrict__ A, const float* __restrict__ W, const float* __restrict__ bias,
    float* __restrict__ C, int N, int Kd) {
  const int r = blockIdx.x;
  const int j = blockIdx.y * 256 + threadIdx.x;
  __shared__ float a[1024];
  for (int e = threadIdx.x; e < Kd; e += 256) a[e] = A[(size_t)r * Kd + e];
  __syncthreads();
  float acc = bias ? bias[j] : 0.f;
  const float4* wr = (const float4*)(W + (size_t)j * Kd);
  const float4* a4 = (const float4*)a;
  for (int e = 0; e < Kd / 4; ++e) {
    float4 wv = wr[e], av = a4[e];
    acc += av.x * wv.x + av.y * wv.y + av.z * wv.z + av.w * wv.w;
  }
  C[(size_t)r * N + j] = acc;
}

// ---------------- cosine sim / TEMP + combine (merged) ----------------
__global__ __launch_bounds__(256) void sim_combine_kernel(
    const float* __restrict__ co, const float* __restrict__ tp,
    const float* __restrict__ lc, const float* __restrict__ ld,
    float* __restrict__ out) {
  const int b = blockIdx.x;
  const int t = threadIdx.x;
  __shared__ float red[4];
  const float* c = co + (size_t)b * 1024;
  const float* p = tp + (size_t)b * 1024;
  float dd = 0.f, nc = 0.f, nt = 0.f;
  for (int e = t; e < 1024; e += 256) {
    const float cv = c[e], pv = p[e];
    dd += cv * pv; nc += cv * cv; nt += pv * pv;
  }
  dd = block_sum(dd, red);
  nc = block_sum(nc, red);
  nt = block_sum(nt, red);
  const float sim = dd / (fmaxf(sqrtf(nc), 1e-12f) * fmaxf(sqrtf(nt), 1e-12f)) / 0.1f;
  if (t < 14) {
    const int i = b * 14 + t;
    const float sup = 0.5f * (lc[i] + ld[i]);
    out[i] = sim;
    out[896 + i] = sup;
    out[1792 + i] = 0.5f * (sup + sim);
  }
}

// ---------------- workspace layout ----------------
static constexpr size_t OFF_X    = 0;
static constexpr size_t OFF_K    = OFF_X + 75497472;   // Kb; later Pm (8.3MB)
static constexpr size_t OFF_SP   = OFF_K + 75759616;   // V-fallback / S
static constexpr size_t OFF_WIN  = OFF_SP + 85082112;
static constexpr size_t OFF_WOUT = OFF_WIN + 6291456;
static constexpr size_t OFF_ASP  = OFF_WOUT + 2097152;
static constexpr size_t OFF_QASP = OFF_ASP + 524288;
static constexpr size_t OFF_ATT  = OFF_QASP + 524288;
static constexpr size_t OFF_APRJ = OFF_ATT + 1835008;
static constexpr size_t OFF_TP   = OFF_APRJ + 3670016;
static constexpr size_t OFF_CV   = OFF_TP + 262144;
static constexpr size_t OFF_CO   = OFF_CV + 262144;
static constexpr size_t OFF_SIM  = OFF_CO + 262144;
static constexpr size_t OFF_LC   = OFF_SIM + 4096;
static constexpr size_t OFF_LD   = OFF_LC + 4096;
static constexpr size_t WS_SMALL = OFF_LD + 4096;
static constexpr size_t OFF_VT   = WS_SMALL;
static constexpr size_t WS_BIG   = OFF_VT + 75497472;

extern "C" void kernel_launch(void* const* d_in, const int* in_sizes, int n_in,
                              void* d_out, int out_size, void* d_ws, size_t ws_size,
                              hipStream_t stream) {
  (void)in_sizes; (void)n_in; (void)out_size;
  const float* vision_features = (const float*)d_in[0];
  const float* text_embeddings = (const float*)d_in[1];
  const float* vision_global   = (const float*)d_in[2];
  const float* aspect_queries  = (const float*)d_in[3];
  const float* ch_in_w  = (const float*)d_in[4];
  const float* ch_in_b  = (const float*)d_in[5];
  const float* ch_out_w = (const float*)d_in[6];
  const float* ch_out_b = (const float*)d_in[7];
  const float* tp_w = (const float*)d_in[8];
  const float* tp_b = (const float*)d_in[9];
  const float* ca_in_w  = (const float*)d_in[10];
  const float* ca_in_b  = (const float*)d_in[11];
  const float* ca_out_w = (const float*)d_in[12];
  const float* ca_out_b = (const float*)d_in[13];
  const float* cross_ln_g = (const float*)d_in[14];
  const float* cross_ln_b = (const float*)d_in[15];
  const float* cross_fc_w = (const float*)d_in[16];
  const float* cross_fc_b = (const float*)d_in[17];
  const float* dir_ln_g = (const float*)d_in[18];
  const float* dir_ln_b = (const float*)d_in[19];
  const float* dir_w1 = (const float*)d_in[20];
  const float* dir_b1 = (const float*)d_in[21];
  const float* dir_w2 = (const float*)d_in[22];
  const float* dir_b2 = (const float*)d_in[23];

  if (ws_size < WS_SMALL) {
    fprintf(stderr, "kernel_launch: ws too small: %zu < %zu\n", ws_size, WS_SMALL);
    return;
  }
  const bool big = (ws_size >= WS_BIG);

  char* ws = (char*)d_ws;
  u16* Xb      = (u16*)(ws + OFF_X);
  u16* Kb      = (u16*)(ws + OFF_K);
  u16* Pm      = (u16*)(ws + OFF_K);   // after S-GEMM, Kb is dead
  u16* Vb      = (u16*)(ws + OFF_SP);
  u16* SP      = (u16*)(ws + OFF_SP);
  u16* Vt      = big ? (u16*)(ws + OFF_VT) : (u16*)(ws + OFF_X);
  u16* Win     = (u16*)(ws + OFF_WIN);
  u16* Wout    = (u16*)(ws + OFF_WOUT);
  u16* Asp     = (u16*)(ws + OFF_ASP);
  u16* Qasp    = (u16*)(ws + OFF_QASP);
  u16* Attd    = (u16*)(ws + OFF_ATT);
  float* Aprj  = (float*)(ws + OFF_APRJ);
  float* Tp    = (float*)(ws + OFF_TP);
  float* Cv2   = (float*)(ws + OFF_CV);
  float* Co    = (float*)(ws + OFF_CO);
  float* Lc    = (float*)(ws + OFF_LC);
  float* Ld    = (float*)(ws + OFF_LD);
  float* attnOut = (float*)d_out + 2688;

  // ---- converts to bf16 ----
  cvt4_kernel<<<3107, 256, 0, stream>>>(vision_features, Xb, ca_in_w, Win,
                                        ca_out_w, Wout, aspect_queries, Asp);

  // ---- fused K+V+Q projections, 256x256 4-phase pipeline ----
  if (big) {
    gemm_kvq_kernel<1><<<dim3(1156), 512, 0, stream>>>(
        Xb, Win + 1024 * 1024, Asp, Win, Kb, nullptr, Vt, Qasp,
        ca_in_b + 1024, ca_in_b);
  } else {
    gemm_kvq_kernel<0><<<dim3(1156), 512, 0, stream>>>(
        Xb, Win + 1024 * 1024, Asp, Win, Kb, Vb, nullptr, Qasp,
        ca_in_b + 1024, ca_in_b);
    transpose_v_kernel<<<dim3(9, 16, 64), 256, 0, stream>>>(Vb, Vt);
  }

  // ---- S = Q K^T / sqrt(128): KT=2, grid (5 n-tiles, 512 bh), bf16 out ----
  gemm_big_kernel<0><<<dim3(5, 512), 512, 0, stream>>>(
      Qasp, Kb, SP, nullptr, 0.08838834764831845f,
      2, 5, 140, 576, 1024, 1024, 576, 8,
      0L, 128L, 589824L, 128L, 663552L, 82944L);

  // ---- softmax (vectorized) + head-mean attnOut + query-mean Pm ----
  softmax_pm_kernel<<<dim3(64, 14), 512, 0, stream>>>(SP, attnOut, Pm);

  // ---- attended = Pm . V  (one head per block) ----
  pv_small_kernel<<<dim3(64, 8), 256, 0, stream>>>(Pm, Vt, Attd);

  // ---- out projection: KT=16, grid (4x8 tiles), f32 out ----
  gemm_big_kernel<1><<<dim3(32, 1), 512, 0, stream>>>(
      Attd, Wout, Aprj, ca_out_b, 1.0f,
      16, 8, 896, 1024, 1024, 1024, 1024, 1,
      0L, 0L, 0L, 0L, 0L, 0L);

  // ---- LN + per-class fc ----
  ln_crossfc_kernel<<<896, 256, 0, stream>>>(Aprj, cross_ln_g, cross_ln_b,
                                             cross_fc_w, cross_fc_b, Lc);

  // ---- direct MLP ----
  direct_mlp_kernel<<<64, 256, 0, stream>>>(vision_global, dir_ln_g, dir_ln_b,
                                            dir_w1, dir_b1, dir_w2, dir_b2, Ld);

  // ---- contrastive chain (f32; 1-key attention is identity) ----
  linear_f32_kernel<<<dim3(64, 4), 256, 0, stream>>>(text_embeddings, tp_w, tp_b, Tp, 1024, 1024);
  linear_f32_kernel<<<dim3(64, 4), 256, 0, stream>>>(Tp, ch_in_w + 2048 * 1024, ch_in_b + 2048, Cv2, 1024, 1024);
  linear_f32_kernel<<<dim3(64, 4), 256, 0, stream>>>(Cv2, ch_out_w, ch_out_b, Co, 1024, 1024);

  // ---- sim + combine (merged) ----
  sim_combine_kernel<<<64, 256, 0, stream>>>(Co, Tp, Lc, Ld, (float*)d_out);
}

// Round 10
// 598.126 us; speedup vs baseline: 1.1619x; 1.0624x over previous
//
#include <hip/hip_runtime.h>
#include <cstdio>
#include <cstdint>

using u16 = unsigned short;
typedef __bf16 bf16x8 __attribute__((ext_vector_type(8)));
typedef float f32x4 __attribute__((ext_vector_type(4)));

#define GLOBAL_AS __attribute__((address_space(1)))
#define LDS_AS __attribute__((address_space(3)))

__device__ __forceinline__ float bf2f(u16 h) {
  return __uint_as_float(((unsigned)h) << 16);
}
__device__ __forceinline__ u16 f2bf(float f) {
  unsigned u = __float_as_uint(f);
  u += 0x7FFFu + ((u >> 16) & 1u);
  return (u16)(u >> 16);
}

__device__ __forceinline__ void async_copy16(void* lds, const void* g) {
  __builtin_amdgcn_global_load_lds((const GLOBAL_AS unsigned int*)g,
                                   (LDS_AS unsigned int*)lds, 16, 0, 0);
}

// ---------------- block reduction helpers (blockDim = 256) ----------------
__device__ __forceinline__ float block_sum(float v, float* red) {
#pragma unroll
  for (int o = 32; o >= 1; o >>= 1) v += __shfl_xor(v, o);
  __syncthreads();
  if ((threadIdx.x & 63) == 0) red[threadIdx.x >> 6] = v;
  __syncthreads();
  return red[0] + red[1] + red[2] + red[3];
}

// ---------------- merged f32 -> bf16 converts (4 ranges, 1 launch) ----------------
__global__ __launch_bounds__(256) void cvt4_kernel(
    const float* __restrict__ s0, u16* __restrict__ d0,
    const float* __restrict__ s1, u16* __restrict__ d1,
    const float* __restrict__ s2, u16* __restrict__ d2,
    const float* __restrict__ s3, u16* __restrict__ d3) {
  const float* s; u16* d; long n; long b0; long nb;
  const int b = blockIdx.x;
  if (b < 2048)      { s = s0; d = d0; n = 37748736L; b0 = b;        nb = 2048; }
  else if (b < 2816) { s = s1; d = d1; n = 3145728L;  b0 = b - 2048; nb = 768; }
  else if (b < 3072) { s = s2; d = d2; n = 1048576L;  b0 = b - 2816; nb = 256; }
  else               { s = s3; d = d3; n = 143360L;   b0 = b - 3072; nb = 35; }
  long i = (b0 * 256 + threadIdx.x) * 4;
  const long stride = nb * 1024;
  for (; i < n; i += stride) {
    float4 v = *(const float4*)(s + i);
    ushort4 o;
    o.x = f2bf(v.x); o.y = f2bf(v.y); o.z = f2bf(v.z); o.w = f2bf(v.w);
    *(ushort4*)(d + i) = o;
  }
}

// =================================================================================
// Fused K+V+Q projection GEMM — 256x256 8-wave 4-phase schedule (round-6 proven).
// =================================================================================
template <int VTD>
__global__ __launch_bounds__(512, 2) void gemm_kvq_kernel(
    const u16* __restrict__ A, const u16* __restrict__ Bkv,
    const u16* __restrict__ Aq, const u16* __restrict__ Bq,
    u16* __restrict__ Ck, u16* __restrict__ Cvp, u16* __restrict__ Vt,
    u16* __restrict__ Cq,
    const float* __restrict__ bias, const float* __restrict__ biasq) {
  __shared__ char smem[131072];  // dbuf d: A at d*65536, B at d*65536+32768
  const int bid = blockIdx.x;
  const int t = threadIdx.x;
  const int wid = t >> 6, l = t & 63;
  const int wm = wid >> 2, wn = wid & 3;
  const int lr = l & 15, lg = l >> 4, lr7 = lr & 7;

  int mt = 0, nt = 0, qb = -1;
  const u16* Abase; const u16* Bbase; const float* bias_b;
  if (bid < 1152) {
    const int wgid = (bid & 7) * 144 + (bid >> 3);  // XCD swizzle (1152 = 8*144)
    mt = wgid >> 3; nt = wgid & 7;                  // nt fastest: A-panel L2 reuse
    Abase = A + (size_t)mt * 256 * 1024;
    Bbase = Bkv + (size_t)nt * 256 * 1024;
    bias_b = bias + nt * 256;
  } else {
    qb = bid - 1152;  // 0..3
    Abase = Aq;
    Bbase = Bq + (size_t)qb * 256 * 1024;
    bias_b = biasq + qb * 256;
  }

  const int srow = t >> 3;
  const int scx = (t & 7) ^ (srow & 7);
  const char* Asrc = (const char*)Abase + (size_t)srow * 2048 + (scx << 4);
  const char* Bsrc = (const char*)Bbase + (size_t)srow * 2048 + (scx << 4);
  const int wb = wid << 10;

  f32x4 acc[8][4] = {};

#define SA(d, r, kt) async_copy16(smem + (d)*65536 + (r)*8192 + wb, \
                                  Asrc + (size_t)(r)*131072 + (size_t)(kt)*128)
#define SB(d, r, kt) async_copy16(smem + (d)*65536 + 32768 + (r)*8192 + wb, \
                                  Bsrc + (size_t)(r)*131072 + (size_t)(kt)*128)

#define RA(d, half)                                                          \
  _Pragma("unroll")                                                          \
  for (int i = 0; i < 4; ++i) {                                              \
    const int row = wm * 128 + ((half)*4 + i) * 16 + lr;                     \
    af[i][0] = *(const bf16x8*)(smem + (d)*65536 + (row << 7) + ((lg ^ lr7) << 4));       \
    af[i][1] = *(const bf16x8*)(smem + (d)*65536 + (row << 7) + (((4 | lg) ^ lr7) << 4)); \
  }

#define RB(d, half)                                                          \
  _Pragma("unroll")                                                          \
  for (int j = 0; j < 2; ++j) {                                              \
    const int row = wn * 64 + ((half)*2 + j) * 16 + lr;                      \
    bfr[j][0] = *(const bf16x8*)(smem + (d)*65536 + 32768 + (row << 7) + ((lg ^ lr7) << 4));       \
    bfr[j][1] = *(const bf16x8*)(smem + (d)*65536 + 32768 + (row << 7) + (((4 | lg) ^ lr7) << 4)); \
  }

#define MM(mh, nh)                                                           \
  __builtin_amdgcn_s_setprio(1);                                             \
  _Pragma("unroll")                                                          \
  for (int ks = 0; ks < 2; ++ks)                                             \
    _Pragma("unroll")                                                        \
    for (int i = 0; i < 4; ++i)                                              \
      _Pragma("unroll")                                                      \
      for (int j = 0; j < 2; ++j)                                            \
        acc[(mh)*4 + i][(nh)*2 + j] = __builtin_amdgcn_mfma_f32_16x16x32_bf16( \
            af[i][ks], bfr[j][ks], acc[(mh)*4 + i][(nh)*2 + j], 0, 0, 0);    \
  __builtin_amdgcn_s_setprio(0);

  SA(0, 0, 0); SA(0, 1, 0); SA(0, 2, 0); SA(0, 3, 0);
  SB(0, 0, 0); SB(0, 1, 0); SB(0, 2, 0); SB(0, 3, 0);
  SA(1, 0, 1); SA(1, 2, 1);
  asm volatile("s_waitcnt vmcnt(2)" ::: "memory");
  __builtin_amdgcn_s_barrier();
  asm volatile("" ::: "memory");

#pragma unroll 1
  for (int kt = 0; kt < 16; ++kt) {
    const int cur = kt & 1, nxt = cur ^ 1;
    const bool pf1 = (kt < 15), pf2 = (kt < 14);
    bf16x8 af[4][2], bfr[2][2];
    RA(cur, 0);
    RB(cur, 0);
    if (pf1) { SB(nxt, 0, kt + 1); SB(nxt, 1, kt + 1); }
    __builtin_amdgcn_s_barrier();
    asm volatile("s_waitcnt lgkmcnt(0)" ::: "memory");
    MM(0, 0);
    __builtin_amdgcn_s_barrier();
    RB(cur, 1);
    if (pf1) { SB(nxt, 2, kt + 1); SB(nxt, 3, kt + 1); }
    __builtin_amdgcn_s_barrier();
    asm volatile("s_waitcnt lgkmcnt(0)" ::: "memory");
    MM(0, 1);
    if (pf1) asm volatile("s_waitcnt vmcnt(6)" ::: "memory");
    __builtin_amdgcn_s_barrier();
    RA(cur, 1);
    if (pf1) { SA(nxt, 1, kt + 1); SA(nxt, 3, kt + 1); }
    __builtin_amdgcn_s_barrier();
    asm volatile("s_waitcnt lgkmcnt(0)" ::: "memory");
    MM(1, 1);
    __builtin_amdgcn_s_barrier();
    RB(cur, 0);
    if (pf2) { SA(cur, 0, kt + 2); SA(cur, 2, kt + 2); }
    __builtin_amdgcn_s_barrier();
    asm volatile("s_waitcnt lgkmcnt(0)" ::: "memory");
    MM(1, 0);
    if (pf2)      asm volatile("s_waitcnt vmcnt(4)" ::: "memory");
    else if (pf1) asm volatile("s_waitcnt vmcnt(0)" ::: "memory");
    __builtin_amdgcn_s_barrier();
  }
#undef SA
#undef SB
#undef RA
#undef RB
#undef MM

  // ---------------- epilogue ----------------
  if (VTD && qb < 0 && nt >= 4) {
    u16* T = (u16*)smem;
    const int vc2 = t >> 1, seg = t & 1;
    const int vglob = (nt - 4) * 256 + vc2;
    const int h2 = vglob >> 7, d2 = vglob & 127;
#pragma unroll 1
    for (int mh = 0; mh < 2; ++mh) {
      __syncthreads();
      if (wm == mh) {
#pragma unroll
        for (int ni = 0; ni < 4; ++ni) {
          const int vc = wn * 64 + ni * 16 + lr;
          const float bv = bias_b[vc];
#pragma unroll
          for (int mi = 0; mi < 8; ++mi) {
            const int ml = mi * 16 + lg * 4;
            ushort4 pk;
            pk.x = f2bf(acc[mi][ni][0] + bv);
            pk.y = f2bf(acc[mi][ni][1] + bv);
            pk.z = f2bf(acc[mi][ni][2] + bv);
            pk.w = f2bf(acc[mi][ni][3] + bv);
            *(ushort4*)(T + (size_t)vc * 136 + ml) = pk;
          }
        }
      }
      __syncthreads();
      const int mg0 = mt * 256 + mh * 128 + seg * 64;
      const int bb = (unsigned)mg0 / 576u;
      const int k0 = mg0 - bb * 576;
      u16* dst = Vt + ((size_t)(bb * 8 + h2) * 128 + d2) * 576 + k0;
      const u16* src = T + (size_t)vc2 * 136 + seg * 64;
#pragma unroll
      for (int i2 = 0; i2 < 8; ++i2)
        *(uint4*)(dst + i2 * 8) = *(const uint4*)(src + i2 * 8);
    }
  } else {
    u16* D; int cb0;
    if (qb >= 0)      { D = Cq;  cb0 = qb * 256; }
    else if (nt < 4)  { D = Ck;  cb0 = nt * 256; }
    else              { D = Cvp; cb0 = (nt - 4) * 256; }
#pragma unroll
    for (int ni = 0; ni < 4; ++ni) {
      const int nc = wn * 64 + ni * 16 + lr;
      const float bv = bias_b[nc];
      const int col = cb0 + nc;
#pragma unroll
      for (int mi = 0; mi < 8; ++mi) {
#pragma unroll
        for (int rg = 0; rg < 4; ++rg) {
          const size_t m = (size_t)mt * 256 + wm * 128 + mi * 16 + lg * 4 + rg;
          D[m * 1024 + col] = f2bf(acc[mi][ni][rg] + bv);
        }
      }
    }
  }
}

// =================================================================================
// Generic deep-pipelined batched GEMM (round-2 proven loop; used for S, out-proj)
// =================================================================================
template <int OUTF32>
__global__ __launch_bounds__(512, 2) void gemm_big_kernel(
    const u16* __restrict__ A, const u16* __restrict__ B, void* __restrict__ Cv,
    const float* __restrict__ bias, float scale,
    int KT, int ntx, int Mlim, int Nlim,
    long lda, long ldb, long ldc, int bdiv,
    long sA0, long sA1, long sB0, long sB1, long sC0, long sC1) {
  __shared__ u16 lds[3][24576];
  const int bid = blockIdx.x;
  const int bh = blockIdx.y;
  const int bb0 = bh / bdiv, bb1 = bh % bdiv;
  const int mt = bid / ntx, nt = bid % ntx;
  const int t = threadIdx.x;
  const int wid = t >> 6, l = t & 63;
  const int wr = wid >> 1, wc = wid & 1;
  const int lr = l & 15, lg = l >> 4, lr7 = lr & 7;

  const long ldab = lda * 2, ldbb = ldb * 2;
  const u16* Abase = A + (long)bb0 * sA0 + (long)bb1 * sA1 + (long)mt * 256 * lda;
  const u16* Bbase = B + (long)bb0 * sB0 + (long)bb1 * sB1 + (long)nt * 128 * ldb;

  const int srow = t >> 3;
  const int scx = (t & 7) ^ (srow & 7);
  const char* Asrc = (const char*)Abase + (long)srow * ldab + (scx << 4);
  const char* Bsrc = (const char*)Bbase + (long)srow * ldbb + (scx << 4);
  const int wbA = wid << 10;

  char* b0 = (char*)lds[0];
  char* b1 = (char*)lds[1];
  char* b2 = (char*)lds[2];

  f32x4 acc[4][4] = {};

#define STAGE3G(dst, kt, part)                                              \
  {                                                                         \
    const long ko = (long)(kt) * 128;                                       \
    if ((part) == 0) {                                                      \
      async_copy16((dst) + wbA,          Asrc + ko);                        \
      async_copy16((dst) + 8192 + wbA,   Asrc + 64 * ldab + ko);            \
      async_copy16((dst) + 16384 + wbA,  Asrc + 128 * ldab + ko);           \
    } else {                                                                \
      async_copy16((dst) + 24576 + wbA,  Asrc + 192 * ldab + ko);           \
      async_copy16((dst) + 32768 + wbA,  Bsrc + ko);                        \
      async_copy16((dst) + 40960 + wbA,  Bsrc + 64 * ldbb + ko);            \
    }                                                                       \
  }

#define COMPUTE_KS(p, KS)                                                   \
  {                                                                         \
    const int ccol = (((KS) << 2) | lg) ^ lr7;                              \
    const char* pA = (p) + (((wr << 6) + lr) << 7) + (ccol << 4);           \
    const char* pB = (p) + 32768 + (((wc << 6) + lr) << 7) + (ccol << 4);   \
    bf16x8 af[4], bfr[4];                                                   \
    _Pragma("unroll")                                                       \
    for (int i = 0; i < 4; ++i) {                                           \
      af[i]  = *(const bf16x8*)(pA + i * 2048);                             \
      bfr[i] = *(const bf16x8*)(pB + i * 2048);                             \
    }                                                                       \
    __builtin_amdgcn_s_setprio(1);                                          \
    _Pragma("unroll")                                                       \
    for (int mi = 0; mi < 4; ++mi)                                          \
      _Pragma("unroll")                                                     \
      for (int ni = 0; ni < 4; ++ni)                                        \
        acc[mi][ni] = __builtin_amdgcn_mfma_f32_16x16x32_bf16(              \
            af[mi], bfr[ni], acc[mi][ni], 0, 0, 0);                         \
    __builtin_amdgcn_s_setprio(0);                                          \
  }

  STAGE3G(b0, 0, 0); STAGE3G(b0, 0, 1);
  STAGE3G(b1, 1, 0); STAGE3G(b1, 1, 1);
  asm volatile("s_waitcnt vmcnt(6)" ::: "memory");
  __builtin_amdgcn_s_barrier();
  asm volatile("" ::: "memory");

  char* p0 = b0; char* p1 = b1; char* p2 = b2;
#pragma unroll 1
  for (int kt = 0; kt < KT; ++kt) {
    const bool pf = (kt < KT - 2);
    if (pf) STAGE3G(p2, kt + 2, 0);
    COMPUTE_KS(p0, 0);
    if (pf) STAGE3G(p2, kt + 2, 1);
    COMPUTE_KS(p0, 1);
    if (kt < KT - 1) {
      if (pf) asm volatile("s_waitcnt vmcnt(6)" ::: "memory");
      else    asm volatile("s_waitcnt vmcnt(0)" ::: "memory");
      __builtin_amdgcn_s_barrier();
      asm volatile("" ::: "memory");
    }
    char* tmp = p0; p0 = p1; p1 = p2; p2 = tmp;
  }
#undef STAGE3G
#undef COMPUTE_KS

  const long cBase = (long)bb0 * sC0 + (long)bb1 * sC1;
  const int mr0 = mt * 256 + wr * 64 + lg * 4;
  const int nc0 = nt * 128 + wc * 64 + lr;
#pragma unroll
  for (int ni = 0; ni < 4; ++ni) {
    const int n = nc0 + ni * 16;
    if (n >= Nlim) continue;
    const float bv = bias ? bias[n] : 0.0f;
#pragma unroll
    for (int mi = 0; mi < 4; ++mi) {
#pragma unroll
      for (int rg = 0; rg < 4; ++rg) {
        const int m = mr0 + mi * 16 + rg;
        if (m >= Mlim) continue;
        const float v = acc[mi][ni][rg] * scale + bv;
        if (OUTF32) ((float*)Cv)[cBase + (long)m * ldc + n] = v;
        else        ((u16*)Cv)[cBase + (long)m * ldc + n] = f2bf(v);
      }
    }
  }
}

// ---------------- V transpose (fallback path only) ----------------
__global__ __launch_bounds__(256) void transpose_v_kernel(const u16* __restrict__ V,
                                                          u16* __restrict__ Vt) {
  __shared__ u16 tile[64][65];
  const int k0 = blockIdx.x * 64;
  const int c0 = blockIdx.y * 64;
  const int b = blockIdx.z;
  const int t = threadIdx.x;
  const int tx = t & 15, ty = t >> 4;
  const u16* Vb = V + (size_t)(b * 576) * 1024;
#pragma unroll
  for (int i = 0; i < 4; ++i) {
    const int k = ty + i * 16;
    const u16* src = Vb + (size_t)(k0 + k) * 1024 + c0 + tx * 4;
    ushort2 v01 = *(const ushort2*)src;
    ushort2 v23 = *(const ushort2*)(src + 2);
    tile[k][tx * 4 + 0] = v01.x; tile[k][tx * 4 + 1] = v01.y;
    tile[k][tx * 4 + 2] = v23.x; tile[k][tx * 4 + 3] = v23.y;
  }
  __syncthreads();
  const int h = c0 >> 7, d0 = c0 & 127;
  u16* VtB = Vt + ((size_t)(b * 8 + h) * 128 + d0) * 576 + k0;
#pragma unroll
  for (int i = 0; i < 4; ++i) {
    const int d = ty + i * 16;
    u16* dst = VtB + (size_t)d * 576 + tx * 4;
    ushort2 a, bb2;
    a.x = tile[tx * 4 + 0][d]; a.y = tile[tx * 4 + 1][d];
    bb2.x = tile[tx * 4 + 2][d]; bb2.y = tile[tx * 4 + 3][d];
    *(ushort2*)dst = a; *(ushort2*)(dst + 2) = bb2;
  }
}

// =================================================================================
// softmax_pm (round-7 proven): softmax over k=576 per (b,h,q) row, no P write-back.
// Block (b,c) = 64 x 14, 512 thr = 8 waves = 8 heads; each wave does the 10
// q-rows of class c for its head. Emits:
//  - attnOut[b, c*10+qq, :]  = mean over h of P        (f32, d_out region)
//  - Pm[((b*8+h)*14+c), :]   = mean over the 10 q of P (bf16) -> feeds pv_small
// =================================================================================
__global__ __launch_bounds__(512) void softmax_pm_kernel(const u16* __restrict__ SP,
                                                         float* __restrict__ attnOut,
                                                         u16* __restrict__ Pm) {
  const int b = blockIdx.x, c = blockIdx.y;
  const int h = threadIdx.x >> 6, l = threadIdx.x & 63;
  __shared__ float pl[8][576];  // 18.4 KB
  float pacc[9] = {};
#pragma unroll 1
  for (int qq = 0; qq < 10; ++qq) {
    const u16* row = SP + ((size_t)((b * 8 + h) * 144 + c * 10 + qq)) * 576;
    float x[9];
#pragma unroll
    for (int i = 0; i < 9; ++i) x[i] = bf2f(row[l + 64 * i]);
    float m = x[0];
#pragma unroll
    for (int i = 1; i < 9; ++i) m = fmaxf(m, x[i]);
#pragma unroll
    for (int o = 32; o >= 1; o >>= 1) m = fmaxf(m, __shfl_xor(m, o));
    float e[9], s = 0.f;
#pragma unroll
    for (int i = 0; i < 9; ++i) { e[i] = expf(x[i] - m); s += e[i]; }
#pragma unroll
    for (int o = 32; o >= 1; o >>= 1) s += __shfl_xor(s, o);
    const float inv = 1.f / s;
#pragma unroll
    for (int i = 0; i < 9; ++i) {
      const float p = e[i] * inv;
      pacc[i] += p;
      pl[h][l + 64 * i] = p;
    }
    __syncthreads();
    // head-mean -> attnOut (512 threads cover 576: j = t and t+512 for t<64)
    float* out = attnOut + ((size_t)(b * 140 + c * 10 + qq)) * 576;
    {
      const int j = threadIdx.x;
      float a = 0.f;
#pragma unroll
      for (int hh = 0; hh < 8; ++hh) a += pl[hh][j];
      out[j] = a * 0.125f;
      if (j < 64) {
        float a2 = 0.f;
#pragma unroll
        for (int hh = 0; hh < 8; ++hh) a2 += pl[hh][j + 512];
        out[j + 512] = a2 * 0.125f;
      }
    }
    __syncthreads();  // pl reused next qq
  }
  // query-mean -> Pm (bf16)
  u16* pm = Pm + ((size_t)((b * 8 + h) * 14 + c)) * 576;
#pragma unroll
  for (int i = 0; i < 9; ++i) pm[l + 64 * i] = f2bf(pacc[i] * 0.1f);
}

// =================================================================================
// pv_small v2 (kept as the single round-8 variable): one head per block,
// grid (64,8), 256 thr = 4 waves; wave w does nf in {2w, 2w+1}.
// =================================================================================
__global__ __launch_bounds__(256) void pv_small_kernel(const u16* __restrict__ Pm,
                                                       const u16* __restrict__ Vt,
                                                       u16* __restrict__ Attd) {
  const int b = blockIdx.x, h = blockIdx.y;
  const int t = threadIdx.x;
  const int w = t >> 6, l = t & 63;
  const int lr = l & 15, lg = l >> 4;
  __shared__ u16 pm[16][584];  // 18688 B; rows 14,15 + chunk 72 zeroed
  for (int i = t; i < 16 * 73; i += 256) {
    const int r = i / 73, ck = i - (i / 73) * 73;
    uint4 v = {0u, 0u, 0u, 0u};
    if (r < 14 && ck < 72)
      v = *(const uint4*)&Pm[((size_t)((b * 8 + h) * 14 + r)) * 576 + ck * 8];
    *(uint4*)&pm[r][ck * 8] = v;
  }
  __syncthreads();
  const u16* vbase = Vt + ((size_t)(b * 8 + h) * 128) * 576;
  f32x4 acc[2] = {};
#pragma unroll 1
  for (int ks = 0; ks < 18; ++ks) {
    const bf16x8 af = *(const bf16x8*)&pm[lr][ks * 32 + lg * 8];
#pragma unroll
    for (int j = 0; j < 2; ++j) {
      const int nf = w * 2 + j;
      const bf16x8 bf = *(const bf16x8*)&vbase[(size_t)(nf * 16 + lr) * 576 + ks * 32 + lg * 8];
      acc[j] = __builtin_amdgcn_mfma_f32_16x16x32_bf16(af, bf, acc[j], 0, 0, 0);
    }
  }
#pragma unroll
  for (int j = 0; j < 2; ++j) {
    const int nf = w * 2 + j;
#pragma unroll
    for (int rg = 0; rg < 4; ++rg) {
      const int cc = lg * 4 + rg;
      if (cc < 14)
        Attd[((size_t)b * 14 + cc) * 1024 + h * 128 + nf * 16 + lr] = f2bf(acc[j][rg]);
    }
  }
}

// ---------------- LN + per-class linear row ----------------
__global__ __launch_bounds__(256) void ln_crossfc_kernel(
    const float* __restrict__ ap, const float* __restrict__ g, const float* __restrict__ bb,
    const float* __restrict__ fw, const float* __restrict__ fb, float* __restrict__ out) {
  const int bc = blockIdx.x;
  const int c = bc % 14;
  const float* x = ap + (size_t)bc * 1024;
  __shared__ float red[4];
  const int t = threadIdx.x;
  float v[4];
  float s = 0.f;
#pragma unroll
  for (int i = 0; i < 4; ++i) { v[i] = x[t + i * 256]; s += v[i]; }
  const float mean = block_sum(s, red) * (1.f / 1024.f);
  float vs = 0.f;
#pragma unroll
  for (int i = 0; i < 4; ++i) { const float d = v[i] - mean; vs += d * d; }
  const float var = block_sum(vs, red) * (1.f / 1024.f);
  const float inv = rsqrtf(var + 1e-5f);
  float acc = 0.f;
#pragma unroll
  for (int i = 0; i < 4; ++i) {
    const int e = t + i * 256;
    const float h = (v[i] - mean) * inv * g[e] + bb[e];
    acc += h * fw[(size_t)c * 1024 + e];
  }
  acc = block_sum(acc, red);
  if (t == 0) out[bc] = acc + fb[c];
}

// ---------------- direct MLP (round-7 proven): LN -> relu(W1) -> W2 ----------------
__global__ __launch_bounds__(256) void direct_mlp_kernel(
    const float* __restrict__ vg, const float* __restrict__ g, const float* __restrict__ bb,
    const float* __restrict__ w1, const float* __restrict__ b1,
    const float* __restrict__ w2, const float* __restrict__ b2, float* __restrict__ out) {
  const int b = blockIdx.x;
  __shared__ float red[4];
  __shared__ float gn[1024];
  __shared__ float h1[512];
  const int t = threadIdx.x;
  const float* x = vg + (size_t)b * 1024;
  float v[4];
  float s = 0.f;
#pragma unroll
  for (int i = 0; i < 4; ++i) { v[i] = x[t + i * 256]; s += v[i]; }
  const float mean = block_sum(s, red) * (1.f / 1024.f);
  float vs = 0.f;
#pragma unroll
  for (int i = 0; i < 4; ++i) { const float d = v[i] - mean; vs += d * d; }
  const float var = block_sum(vs, red) * (1.f / 1024.f);
  const float inv = rsqrtf(var + 1e-5f);
#pragma unroll
  for (int i = 0; i < 4; ++i) {
    const int e = t + i * 256;
    gn[e] = (v[i] - mean) * inv * g[e] + bb[e];
  }
  __syncthreads();
  for (int j = t; j < 512; j += 256) {
    float a = b1[j];
    const float4* wr = (const float4*)(w1 + (size_t)j * 1024);
    const float4* g4 = (const float4*)gn;
    for (int e = 0; e < 256; ++e) {
      float4 wv = wr[e], av = g4[e];
      a += av.x * wv.x + av.y * wv.y + av.z * wv.z + av.w * wv.w;
    }
    h1[j] = fmaxf(a, 0.f);
  }
  __syncthreads();
  for (int c = 0; c < 14; ++c) {
    float a = 0.f;
    for (int j = t; j < 512; j += 256) a += h1[j] * w2[(size_t)c * 512 + j];
    a = block_sum(a, red);
    if (t == 0) out[b * 14 + c] = a + b2[c];
  }
}

// ---------------- small f32 linear (round-7 proven: 1 row/block, grid (64,4)) ----------------
__global__ __launch_bounds__(256) void linear_f32_kernel(
    const float* __restrict__ A, const float* __restrict__ W, const float* __restrict__ bias,
    float* __restrict__ C, int N, int Kd) {
  const int r = blockIdx.x;
  const int j = blockIdx.y * 256 + threadIdx.x;
  __shared__ float a[1024];
  for (int e = threadIdx.x; e < Kd; e += 256) a[e] = A[(size_t)r * Kd + e];
  __syncthreads();
  float acc = bias ? bias[j] : 0.f;
  const float4* wr = (const float4*)(W + (size_t)j * Kd);
  const float4* a4 = (const float4*)a;
  for (int e = 0; e < Kd / 4; ++e) {
    float4 wv = wr[e], av = a4[e];
    acc += av.x * wv.x + av.y * wv.y + av.z * wv.z + av.w * wv.w;
  }
  C[(size_t)r * N + j] = acc;
}

// ---------------- cosine sim / TEMP + combine (merged) ----------------
__global__ __launch_bounds__(256) void sim_combine_kernel(
    const float* __restrict__ co, const float* __restrict__ tp,
    const float* __restrict__ lc, const float* __restrict__ ld,
    float* __restrict__ out) {
  const int b = blockIdx.x;
  const int t = threadIdx.x;
  __shared__ float red[4];
  const float* c = co + (size_t)b * 1024;
  const float* p = tp + (size_t)b * 1024;
  float dd = 0.f, nc = 0.f, nt = 0.f;
  for (int e = t; e < 1024; e += 256) {
    const float cv = c[e], pv = p[e];
    dd += cv * pv; nc += cv * cv; nt += pv * pv;
  }
  dd = block_sum(dd, red);
  nc = block_sum(nc, red);
  nt = block_sum(nt, red);
  const float sim = dd / (fmaxf(sqrtf(nc), 1e-12f) * fmaxf(sqrtf(nt), 1e-12f)) / 0.1f;
  if (t < 14) {
    const int i = b * 14 + t;
    const float sup = 0.5f * (lc[i] + ld[i]);
    out[i] = sim;
    out[896 + i] = sup;
    out[1792 + i] = 0.5f * (sup + sim);
  }
}

// ---------------- workspace layout ----------------
static constexpr size_t OFF_X    = 0;
static constexpr size_t OFF_K    = OFF_X + 75497472;   // Kb; later Pm (8.3MB)
static constexpr size_t OFF_SP   = OFF_K + 75759616;   // V-fallback / S
static constexpr size_t OFF_WIN  = OFF_SP + 85082112;
static constexpr size_t OFF_WOUT = OFF_WIN + 6291456;
static constexpr size_t OFF_ASP  = OFF_WOUT + 2097152;
static constexpr size_t OFF_QASP = OFF_ASP + 524288;
static constexpr size_t OFF_ATT  = OFF_QASP + 524288;
static constexpr size_t OFF_APRJ = OFF_ATT + 1835008;
static constexpr size_t OFF_TP   = OFF_APRJ + 3670016;
static constexpr size_t OFF_CV   = OFF_TP + 262144;
static constexpr size_t OFF_CO   = OFF_CV + 262144;
static constexpr size_t OFF_SIM  = OFF_CO + 262144;
static constexpr size_t OFF_LC   = OFF_SIM + 4096;
static constexpr size_t OFF_LD   = OFF_LC + 4096;
static constexpr size_t WS_SMALL = OFF_LD + 4096;
static constexpr size_t OFF_VT   = WS_SMALL;
static constexpr size_t WS_BIG   = OFF_VT + 75497472;

extern "C" void kernel_launch(void* const* d_in, const int* in_sizes, int n_in,
                              void* d_out, int out_size, void* d_ws, size_t ws_size,
                              hipStream_t stream) {
  (void)in_sizes; (void)n_in; (void)out_size;
  const float* vision_features = (const float*)d_in[0];
  const float* text_embeddings = (const float*)d_in[1];
  const float* vision_global   = (const float*)d_in[2];
  const float* aspect_queries  = (const float*)d_in[3];
  const float* ch_in_w  = (const float*)d_in[4];
  const float* ch_in_b  = (const float*)d_in[5];
  const float* ch_out_w = (const float*)d_in[6];
  const float* ch_out_b = (const float*)d_in[7];
  const float* tp_w = (const float*)d_in[8];
  const float* tp_b = (const float*)d_in[9];
  const float* ca_in_w  = (const float*)d_in[10];
  const float* ca_in_b  = (const float*)d_in[11];
  const float* ca_out_w = (const float*)d_in[12];
  const float* ca_out_b = (const float*)d_in[13];
  const float* cross_ln_g = (const float*)d_in[14];
  const float* cross_ln_b = (const float*)d_in[15];
  const float* cross_fc_w = (const float*)d_in[16];
  const float* cross_fc_b = (const float*)d_in[17];
  const float* dir_ln_g = (const float*)d_in[18];
  const float* dir_ln_b = (const float*)d_in[19];
  const float* dir_w1 = (const float*)d_in[20];
  const float* dir_b1 = (const float*)d_in[21];
  const float* dir_w2 = (const float*)d_in[22];
  const float* dir_b2 = (const float*)d_in[23];

  if (ws_size < WS_SMALL) {
    fprintf(stderr, "kernel_launch: ws too small: %zu < %zu\n", ws_size, WS_SMALL);
    return;
  }
  const bool big = (ws_size >= WS_BIG);

  char* ws = (char*)d_ws;
  u16* Xb      = (u16*)(ws + OFF_X);
  u16* Kb      = (u16*)(ws + OFF_K);
  u16* Pm      = (u16*)(ws + OFF_K);   // after S-GEMM, Kb is dead
  u16* Vb      = (u16*)(ws + OFF_SP);
  u16* SP      = (u16*)(ws + OFF_SP);
  u16* Vt      = big ? (u16*)(ws + OFF_VT) : (u16*)(ws + OFF_X);
  u16* Win     = (u16*)(ws + OFF_WIN);
  u16* Wout    = (u16*)(ws + OFF_WOUT);
  u16* Asp     = (u16*)(ws + OFF_ASP);
  u16* Qasp    = (u16*)(ws + OFF_QASP);
  u16* Attd    = (u16*)(ws + OFF_ATT);
  float* Aprj  = (float*)(ws + OFF_APRJ);
  float* Tp    = (float*)(ws + OFF_TP);
  float* Cv2   = (float*)(ws + OFF_CV);
  float* Co    = (float*)(ws + OFF_CO);
  float* Lc    = (float*)(ws + OFF_LC);
  float* Ld    = (float*)(ws + OFF_LD);
  float* attnOut = (float*)d_out + 2688;

  // ---- converts to bf16 ----
  cvt4_kernel<<<3107, 256, 0, stream>>>(vision_features, Xb, ca_in_w, Win,
                                        ca_out_w, Wout, aspect_queries, Asp);

  // ---- fused K+V+Q projections, 256x256 4-phase pipeline ----
  if (big) {
    gemm_kvq_kernel<1><<<dim3(1156), 512, 0, stream>>>(
        Xb, Win + 1024 * 1024, Asp, Win, Kb, nullptr, Vt, Qasp,
        ca_in_b + 1024, ca_in_b);
  } else {
    gemm_kvq_kernel<0><<<dim3(1156), 512, 0, stream>>>(
        Xb, Win + 1024 * 1024, Asp, Win, Kb, Vb, nullptr, Qasp,
        ca_in_b + 1024, ca_in_b);
    transpose_v_kernel<<<dim3(9, 16, 64), 256, 0, stream>>>(Vb, Vt);
  }

  // ---- S = Q K^T / sqrt(128): KT=2, grid (5 n-tiles, 512 bh), bf16 out ----
  gemm_big_kernel<0><<<dim3(5, 512), 512, 0, stream>>>(
      Qasp, Kb, SP, nullptr, 0.08838834764831845f,
      2, 5, 140, 576, 1024, 1024, 576, 8,
      0L, 128L, 589824L, 128L, 663552L, 82944L);

  // ---- softmax (round-7) + head-mean attnOut + query-mean Pm ----
  softmax_pm_kernel<<<dim3(64, 14), 512, 0, stream>>>(SP, attnOut, Pm);

  // ---- attended = Pm . V  (pv_small v2: one head per block) ----
  pv_small_kernel<<<dim3(64, 8), 256, 0, stream>>>(Pm, Vt, Attd);

  // ---- out projection: KT=16, grid (4x8 tiles), f32 out ----
  gemm_big_kernel<1><<<dim3(32, 1), 512, 0, stream>>>(
      Attd, Wout, Aprj, ca_out_b, 1.0f,
      16, 8, 896, 1024, 1024, 1024, 1024, 1,
      0L, 0L, 0L, 0L, 0L, 0L);

  // ---- LN + per-class fc ----
  ln_crossfc_kernel<<<896, 256, 0, stream>>>(Aprj, cross_ln_g, cross_ln_b,
                                             cross_fc_w, cross_fc_b, Lc);

  // ---- direct MLP ----
  direct_mlp_kernel<<<64, 256, 0, stream>>>(vision_global, dir_ln_g, dir_ln_b,
                                            dir_w1, dir_b1, dir_w2, dir_b2, Ld);

  // ---- contrastive chain (f32; 1-key attention is identity) ----
  linear_f32_kernel<<<dim3(64, 4), 256, 0, stream>>>(text_embeddings, tp_w, tp_b, Tp, 1024, 1024);
  linear_f32_kernel<<<dim3(64, 4), 256, 0, stream>>>(Tp, ch_in_w + 2048 * 1024, ch_in_b + 2048, Cv2, 1024, 1024);
  linear_f32_kernel<<<dim3(64, 4), 256, 0, stream>>>(Cv2, ch_out_w, ch_out_b, Co, 1024, 1024);

  // ---- sim + combine (merged) ----
  sim_combine_kernel<<<64, 256, 0, stream>>>(Co, Tp, Lc, Ld, (float*)d_out);
}